// Round 1
// baseline (678.240 us; speedup 1.0000x reference)
//
#include <hip/hip_runtime.h>
#include <cstdint>
#include <cstddef>

// ---------------- problem constants ----------------
#define S_LEN 2048
#define HID   3584
#define NH    28
#define NKV   4
#define DHEAD 128
#define QKV_N 4608   /* 3584 Q + 512 K + 512 V */
#define GROUPS 7

typedef __attribute__((ext_vector_type(8))) short  short8;   // 8 bf16 (4 VGPRs)
typedef __attribute__((ext_vector_type(4))) float  f32x4;    // MFMA accumulator

__device__ __forceinline__ unsigned short f2bf(float f) {
  unsigned int u = __builtin_bit_cast(unsigned int, f);
  u += 0x7FFFu + ((u >> 16) & 1u);            // RNE
  return (unsigned short)(u >> 16);
}
__device__ __forceinline__ float bf2f(unsigned short b) {
  unsigned int u = ((unsigned int)b) << 16;
  return __builtin_bit_cast(float, u);
}
// async global->LDS, 16B/lane. lds ptr must be wave-uniform; HW adds lane*16.
__device__ __forceinline__ void gload_lds16(const void* g, void* l) {
  __builtin_amdgcn_global_load_lds(
      (const __attribute__((address_space(1))) unsigned int*)g,
      (__attribute__((address_space(3))) unsigned int*)l, 16, 0, 0);
}

// ---------------- fp32 -> bf16 elementwise convert ----------------
__global__ void conv_f32_bf16(const float* __restrict__ in,
                              unsigned short* __restrict__ out, int n) {
  int i = (blockIdx.x * blockDim.x + threadIdx.x) * 4;
  int stride = gridDim.x * blockDim.x * 4;
  for (; i < n; i += stride) {
    float4 v = *(const float4*)&in[i];
    ushort4 o;
    o.x = f2bf(v.x); o.y = f2bf(v.y); o.z = f2bf(v.z); o.w = f2bf(v.w);
    *(ushort4*)&out[i] = o;
  }
}

// ---------------- transpose + convert: W[K][N] f32 -> Wt[N][K] bf16 ----------
__global__ void transpose_conv(const float* __restrict__ W,
                               unsigned short* __restrict__ Wt, int K, int N) {
  __shared__ float tile[32][33];
  int n0 = blockIdx.x * 32, k0 = blockIdx.y * 32;
  int tx = threadIdx.x, ty = threadIdx.y;          // block (32,8)
#pragma unroll
  for (int i = 0; i < 4; ++i)
    tile[ty + i * 8][tx] = W[(size_t)(k0 + ty + i * 8) * N + n0 + tx];
  __syncthreads();
#pragma unroll
  for (int i = 0; i < 4; ++i)
    Wt[(size_t)(n0 + ty + i * 8) * K + k0 + tx] = f2bf(tile[tx][ty + i * 8]);
}

// ---------------- bias concat [q_b | k_b | v_b] -> fp32[4608] ----------------
__global__ void concat_bias(const float* __restrict__ qb, const float* __restrict__ kb,
                            const float* __restrict__ vb, float* __restrict__ out) {
  int i = blockIdx.x * blockDim.x + threadIdx.x;
  if (i < HID) out[i] = qb[i];
  else if (i < HID + 512) out[i] = kb[i - HID];
  else if (i < QKV_N) out[i] = vb[i - HID - 512];
}

// ---------------- RoPE cos/sin table: [2048][64] each ----------------
__global__ void rope_table(const int* __restrict__ pos, float* __restrict__ ct,
                           float* __restrict__ st) {
  int p = blockIdx.x, i = threadIdx.x;            // 64 threads
  float pf = (float)pos[p];
  // inv_freq = 1e6^(-i/64) = exp(-i * ln(1e6)/64)
  float inv = __expf(-(float)i * (13.815510557964274f / 64.0f));
  float f = pf * inv;
  ct[p * 64 + i] = cosf(f);
  st[p * 64 + i] = sinf(f);
}

// ---------------- RoPE apply in-place on Q,K halves of QKV ----------------
__global__ void rope_apply(unsigned short* __restrict__ QKV,
                           const float* __restrict__ ct, const float* __restrict__ st) {
  int idx = blockIdx.x * blockDim.x + threadIdx.x;  // 2048 * 32 * 64 total
  int i  = idx & 63;
  int hs = (idx >> 6) & 31;                         // 0..27 Q heads, 28..31 K heads
  int s  = idx >> 11;
  int cb = hs < NH ? hs * DHEAD : HID + (hs - NH) * DHEAD;
  size_t base = (size_t)s * QKV_N + cb;
  float x1 = bf2f(QKV[base + i]);
  float x2 = bf2f(QKV[base + 64 + i]);
  float c = ct[s * 64 + i], sn = st[s * 64 + i];
  QKV[base + i]      = f2bf(x1 * c - x2 * sn);
  QKV[base + 64 + i] = f2bf(x2 * c + x1 * sn);
}

// ---------------- bf16 GEMM (m97 structure): C = A[M][K] @ Bt[N][K]^T (+bias) --
template <bool HAS_BIAS, bool OUT_F32>
__global__ __launch_bounds__(256) void gemm_bt(
    const unsigned short* __restrict__ A, const unsigned short* __restrict__ Bt,
    const float* __restrict__ bias, void* __restrict__ Cout, int M, int N, int K) {
  __shared__ unsigned short As[128 * 64];
  __shared__ unsigned short Bs[128 * 64];
  const int tid = threadIdx.x;
  const int wid = tid >> 6, lane = tid & 63;
  const int l16 = lane & 15, lg = lane >> 4;
  const int brow = blockIdx.y * 128, bcol = blockIdx.x * 128;
  const int wr = (wid >> 1) * 64, wc = (wid & 1) * 64;

  f32x4 acc[4][4] = {};
  const int nk = K >> 6;
  for (int kt = 0; kt < nk; ++kt) {
    const int k0 = kt << 6;
#pragma unroll
    for (int it = 0; it < 4; ++it) {
      int e = it * 2048 + wid * 512 + lane * 8;   // element index in 128x64 tile
      int r = e >> 6, c = e & 63;
      gload_lds16(A + (size_t)(brow + r) * K + k0 + c,
                  (char*)As + it * 4096 + wid * 1024);
      gload_lds16(Bt + (size_t)(bcol + r) * K + k0 + c,
                  (char*)Bs + it * 4096 + wid * 1024);
    }
    __syncthreads();
#pragma unroll
    for (int kk = 0; kk < 2; ++kk) {
      short8 a[4], b[4];
#pragma unroll
      for (int m = 0; m < 4; ++m)
        a[m] = *(const short8*)&As[(wr + m * 16 + l16) * 64 + kk * 32 + lg * 8];
#pragma unroll
      for (int n = 0; n < 4; ++n)
        b[n] = *(const short8*)&Bs[(wc + n * 16 + l16) * 64 + kk * 32 + lg * 8];
#pragma unroll
      for (int m = 0; m < 4; ++m)
#pragma unroll
        for (int n = 0; n < 4; ++n)
          acc[m][n] = __builtin_amdgcn_mfma_f32_16x16x32_bf16(a[m], b[n], acc[m][n], 0, 0, 0);
    }
    __syncthreads();
  }
#pragma unroll
  for (int m = 0; m < 4; ++m) {
    int row = brow + wr + m * 16 + lg * 4;
#pragma unroll
    for (int n = 0; n < 4; ++n) {
      int col = bcol + wc + n * 16 + l16;
      float bv = HAS_BIAS ? bias[col] : 0.f;
#pragma unroll
      for (int r = 0; r < 4; ++r) {
        float v = acc[m][n][r] + bv;
        if constexpr (OUT_F32)
          ((float*)Cout)[(size_t)(row + r) * N + col] = v;
        else
          ((unsigned short*)Cout)[(size_t)(row + r) * N + col] = f2bf(v);
      }
    }
  }
}

// ---------------- flash attention (causal, GQA 7:1) ----------------
// grid (16 q-tiles, 28 heads), 256 threads = 4 waves, wave = 32 q-rows.
__global__ __launch_bounds__(256) void attn(const unsigned short* __restrict__ QKV,
                                            unsigned short* __restrict__ ctx) {
  __shared__ unsigned short Ks[64][136];   // K tile [kv][d], padded (16B-aligned rows)
  __shared__ unsigned short Vt[128][72];   // V tile transposed [d][kv], padded
  __shared__ unsigned short Ps[4][32][72]; // per-wave P [q][kv], padded
  const int tid = threadIdx.x, wid = tid >> 6, lane = tid & 63;
  const int l16 = lane & 15, lg = lane >> 4;
  const int qt = blockIdx.x, h = blockIdx.y;
  const int kvh = h / GROUPS;
  const int qbase = qt * 128 + wid * 32;
  const int koff = HID + kvh * DHEAD, voff = HID + 512 + kvh * DHEAD;
  const float SCALE = 0.08838834764831845f;     // 1/sqrt(128)

  // Q fragments in registers: rows qbase + rb*16 + l16, k = kb*32 + lg*8
  short8 qf[2][4];
#pragma unroll
  for (int rb = 0; rb < 2; ++rb) {
    int row = qbase + rb * 16 + l16;
#pragma unroll
    for (int kb = 0; kb < 4; ++kb)
      qf[rb][kb] = *(const short8*)&QKV[(size_t)row * QKV_N + h * DHEAD + kb * 32 + lg * 8];
  }
  f32x4 of[2][8] = {};
  float mrun[2][4], lrun[2][4];
#pragma unroll
  for (int rb = 0; rb < 2; ++rb)
#pragma unroll
    for (int r = 0; r < 4; ++r) { mrun[rb][r] = -INFINITY; lrun[rb][r] = 0.f; }

  const int nkt = 2 * qt + 2;
  for (int kt = 0; kt < nkt; ++kt) {
    // ---- stage K (row-major padded) and V (transposed) ----
#pragma unroll
    for (int p = 0; p < 4; ++p) {
      int r = p * 16 + (tid >> 4);     // kv row in tile
      int c = (tid & 15) * 8;          // d offset
      size_t grow = (size_t)(kt * 64 + r) * QKV_N;
      uint4 kk = *(const uint4*)&QKV[grow + koff + c];
      *(uint4*)&Ks[r][c] = kk;
      uint4 vv = *(const uint4*)&QKV[grow + voff + c];
      const unsigned short* vs = (const unsigned short*)&vv;
#pragma unroll
      for (int j = 0; j < 8; ++j) Vt[c + j][r] = vs[j];
    }
    __syncthreads();

    // ---- S = (Q K^T) ----
    f32x4 s[2][4] = {};
#pragma unroll
    for (int kb = 0; kb < 4; ++kb) {
      short8 b[4];
#pragma unroll
      for (int cb = 0; cb < 4; ++cb)
        b[cb] = *(const short8*)&Ks[cb * 16 + l16][kb * 32 + lg * 8];
#pragma unroll
      for (int rb = 0; rb < 2; ++rb)
#pragma unroll
        for (int cb = 0; cb < 4; ++cb)
          s[rb][cb] = __builtin_amdgcn_mfma_f32_16x16x32_bf16(qf[rb][kb], b[cb], s[rb][cb], 0, 0, 0);
    }

    const bool need_mask = (kt * 64 + 63) > qbase;
#pragma unroll
    for (int rb = 0; rb < 2; ++rb) {
      float rmax[4], rsum[4], mnew[4], alpha[4];
#pragma unroll
      for (int r = 0; r < 4; ++r) rmax[r] = -INFINITY;
#pragma unroll
      for (int cb = 0; cb < 4; ++cb)
#pragma unroll
        for (int r = 0; r < 4; ++r) {
          float v = s[rb][cb][r] * SCALE;
          if (need_mask) {
            int qg = qbase + rb * 16 + lg * 4 + r;
            int kg = kt * 64 + cb * 16 + l16;
            if (kg > qg) v = -1e30f;
          }
          s[rb][cb][r] = v;
          rmax[r] = fmaxf(rmax[r], v);
        }
#pragma unroll
      for (int r = 0; r < 4; ++r) {
#pragma unroll
        for (int msk = 1; msk < 16; msk <<= 1)
          rmax[r] = fmaxf(rmax[r], __shfl_xor(rmax[r], msk, 64));
        mnew[r] = fmaxf(mrun[rb][r], rmax[r]);
        alpha[r] = __expf(mrun[rb][r] - mnew[r]);
        rsum[r] = 0.f;
      }
#pragma unroll
      for (int cb = 0; cb < 4; ++cb)
#pragma unroll
        for (int r = 0; r < 4; ++r) {
          float p = __expf(s[rb][cb][r] - mnew[r]);
          s[rb][cb][r] = p;
          rsum[r] += p;
        }
#pragma unroll
      for (int r = 0; r < 4; ++r) {
#pragma unroll
        for (int msk = 1; msk < 16; msk <<= 1)
          rsum[r] += __shfl_xor(rsum[r], msk, 64);
        lrun[rb][r] = lrun[rb][r] * alpha[r] + rsum[r];
        mrun[rb][r] = mnew[r];
      }
#pragma unroll
      for (int nb = 0; nb < 8; ++nb)
#pragma unroll
        for (int r = 0; r < 4; ++r) of[rb][nb][r] *= alpha[r];
      // C-frag -> LDS so PV can read A-frags (re-layout)
#pragma unroll
      for (int cb = 0; cb < 4; ++cb)
#pragma unroll
        for (int r = 0; r < 4; ++r)
          Ps[wid][rb * 16 + lg * 4 + r][cb * 16 + l16] = f2bf(s[rb][cb][r]);
    }

    // ---- PV ----
#pragma unroll
    for (int kb = 0; kb < 2; ++kb) {
      short8 pa[2];
#pragma unroll
      for (int rb = 0; rb < 2; ++rb)
        pa[rb] = *(const short8*)&Ps[wid][rb * 16 + l16][kb * 32 + lg * 8];
#pragma unroll
      for (int nb = 0; nb < 8; ++nb) {
        short8 vb = *(const short8*)&Vt[nb * 16 + l16][kb * 32 + lg * 8];
#pragma unroll
        for (int rb = 0; rb < 2; ++rb)
          of[rb][nb] = __builtin_amdgcn_mfma_f32_16x16x32_bf16(pa[rb], vb, of[rb][nb], 0, 0, 0);
      }
    }
    __syncthreads();
  }

  // ---- epilogue: ctx[s][h*128+d] ----
#pragma unroll
  for (int rb = 0; rb < 2; ++rb)
#pragma unroll
    for (int r = 0; r < 4; ++r) {
      float inv = 1.f / lrun[rb][r];
      int row = qbase + rb * 16 + lg * 4 + r;
#pragma unroll
      for (int nb = 0; nb < 8; ++nb)
        ctx[(size_t)row * HID + h * DHEAD + nb * 16 + l16] = f2bf(of[rb][nb][r] * inv);
    }
}

// ---------------- host launch ----------------
extern "C" void kernel_launch(void* const* d_in, const int* in_sizes, int n_in,
                              void* d_out, int out_size, void* d_ws, size_t ws_size,
                              hipStream_t stream) {
  (void)in_sizes; (void)n_in; (void)out_size; (void)ws_size;
  const float* X   = (const float*)d_in[0];
  const int*   pos = (const int*)d_in[1];
  const float* qw  = (const float*)d_in[2];
  const float* qb  = (const float*)d_in[3];
  const float* kw  = (const float*)d_in[4];
  const float* kb  = (const float*)d_in[5];
  const float* vw  = (const float*)d_in[6];
  const float* vb  = (const float*)d_in[7];
  const float* ow  = (const float*)d_in[8];
  float* out = (float*)d_out;

  char* w = (char*)d_ws;
  unsigned short* Xb    = (unsigned short*)w; w += (size_t)S_LEN * HID * 2;
  unsigned short* Wqkvt = (unsigned short*)w; w += (size_t)QKV_N * HID * 2;
  unsigned short* Wot   = (unsigned short*)w; w += (size_t)HID * HID * 2;
  float*          bqkv  = (float*)w;          w += (size_t)QKV_N * 4;
  unsigned short* QKV   = (unsigned short*)w; w += (size_t)S_LEN * QKV_N * 2;
  float*          ct    = (float*)w;          w += (size_t)S_LEN * 64 * 4;
  float*          st    = (float*)w;          w += (size_t)S_LEN * 64 * 4;
  unsigned short* ctx   = (unsigned short*)w; w += (size_t)S_LEN * HID * 2;

  conv_f32_bf16<<<2048, 256, 0, stream>>>(X, Xb, S_LEN * HID);
  transpose_conv<<<dim3(112, 112), dim3(32, 8), 0, stream>>>(qw, Wqkvt, HID, HID);
  transpose_conv<<<dim3(16, 112),  dim3(32, 8), 0, stream>>>(kw, Wqkvt + (size_t)HID * HID, HID, 512);
  transpose_conv<<<dim3(16, 112),  dim3(32, 8), 0, stream>>>(vw, Wqkvt + (size_t)(HID + 512) * HID, HID, 512);
  transpose_conv<<<dim3(112, 112), dim3(32, 8), 0, stream>>>(ow, Wot, HID, HID);
  concat_bias<<<18, 256, 0, stream>>>(qb, kb, vb, bqkv);
  rope_table<<<S_LEN, 64, 0, stream>>>(pos, ct, st);

  gemm_bt<true, false><<<dim3(QKV_N / 128, S_LEN / 128), 256, 0, stream>>>(
      Xb, Wqkvt, bqkv, QKV, S_LEN, QKV_N, HID);
  rope_apply<<<(S_LEN * 32 * 64) / 256, 256, 0, stream>>>(QKV, ct, st);
  attn<<<dim3(S_LEN / 128, NH), 256, 0, stream>>>(QKV, ctx);
  gemm_bt<false, true><<<dim3(HID / 128, S_LEN / 128), 256, 0, stream>>>(
      ctx, Wot, nullptr, out, S_LEN, HID, HID);
}

// Round 2
// 585.418 us; speedup vs baseline: 1.1586x; 1.1586x over previous
//
#include <hip/hip_runtime.h>
#include <cstdint>
#include <cstddef>

// ---------------- problem constants ----------------
#define S_LEN 2048
#define HID   3584
#define NH    28
#define NKV   4
#define DHEAD 128
#define QKV_N 4608   /* 3584 Q + 512 K + 512 V */
#define GROUPS 7

typedef __attribute__((ext_vector_type(8))) short  short8;   // 8 bf16 (4 VGPRs)
typedef __attribute__((ext_vector_type(4))) float  f32x4;    // MFMA accumulator

__device__ __forceinline__ unsigned short f2bf(float f) {
  unsigned int u = __builtin_bit_cast(unsigned int, f);
  u += 0x7FFFu + ((u >> 16) & 1u);            // RNE
  return (unsigned short)(u >> 16);
}
__device__ __forceinline__ float bf2f(unsigned short b) {
  unsigned int u = ((unsigned int)b) << 16;
  return __builtin_bit_cast(float, u);
}
// async global->LDS, 16B/lane. lds ptr must be wave-uniform; HW adds lane*16.
__device__ __forceinline__ void gload_lds16(const void* g, void* l) {
  __builtin_amdgcn_global_load_lds(
      (const __attribute__((address_space(1))) unsigned int*)g,
      (__attribute__((address_space(3))) unsigned int*)l, 16, 0, 0);
}

// ---------------- fp32 -> bf16 elementwise convert ----------------
__global__ void conv_f32_bf16(const float* __restrict__ in,
                              unsigned short* __restrict__ out, int n) {
  int i = (blockIdx.x * blockDim.x + threadIdx.x) * 4;
  int stride = gridDim.x * blockDim.x * 4;
  for (; i < n; i += stride) {
    float4 v = *(const float4*)&in[i];
    ushort4 o;
    o.x = f2bf(v.x); o.y = f2bf(v.y); o.z = f2bf(v.z); o.w = f2bf(v.w);
    *(ushort4*)&out[i] = o;
  }
}

// ---------------- transpose + convert: W[K][N] f32 -> Wt[N][K] bf16 ----------
__global__ void transpose_conv(const float* __restrict__ W,
                               unsigned short* __restrict__ Wt, int K, int N) {
  __shared__ float tile[32][33];
  int n0 = blockIdx.x * 32, k0 = blockIdx.y * 32;
  int tx = threadIdx.x, ty = threadIdx.y;          // block (32,8)
#pragma unroll
  for (int i = 0; i < 4; ++i)
    tile[ty + i * 8][tx] = W[(size_t)(k0 + ty + i * 8) * N + n0 + tx];
  __syncthreads();
#pragma unroll
  for (int i = 0; i < 4; ++i)
    Wt[(size_t)(n0 + ty + i * 8) * K + k0 + tx] = f2bf(tile[tx][ty + i * 8]);
}

// ---------------- bias concat [q_b | k_b | v_b] -> fp32[4608] ----------------
__global__ void concat_bias(const float* __restrict__ qb, const float* __restrict__ kb,
                            const float* __restrict__ vb, float* __restrict__ out) {
  int i = blockIdx.x * blockDim.x + threadIdx.x;
  if (i < HID) out[i] = qb[i];
  else if (i < HID + 512) out[i] = kb[i - HID];
  else if (i < QKV_N) out[i] = vb[i - HID - 512];
}

// ---------------- RoPE cos/sin table: [2048][64] each ----------------
__global__ void rope_table(const int* __restrict__ pos, float* __restrict__ ct,
                           float* __restrict__ st) {
  int p = blockIdx.x, i = threadIdx.x;            // 64 threads
  float pf = (float)pos[p];
  // inv_freq = 1e6^(-i/64) = exp(-i * ln(1e6)/64)
  float inv = __expf(-(float)i * (13.815510557964274f / 64.0f));
  float f = pf * inv;
  ct[p * 64 + i] = cosf(f);
  st[p * 64 + i] = sinf(f);
}

// ---------------- RoPE apply in-place on Q,K halves of QKV ----------------
__global__ void rope_apply(unsigned short* __restrict__ QKV,
                           const float* __restrict__ ct, const float* __restrict__ st) {
  int idx = blockIdx.x * blockDim.x + threadIdx.x;  // 2048 * 32 * 64 total
  int i  = idx & 63;
  int hs = (idx >> 6) & 31;                         // 0..27 Q heads, 28..31 K heads
  int s  = idx >> 11;
  int cb = hs < NH ? hs * DHEAD : HID + (hs - NH) * DHEAD;
  size_t base = (size_t)s * QKV_N + cb;
  float x1 = bf2f(QKV[base + i]);
  float x2 = bf2f(QKV[base + 64 + i]);
  float c = ct[s * 64 + i], sn = st[s * 64 + i];
  QKV[base + i]      = f2bf(x1 * c - x2 * sn);
  QKV[base + 64 + i] = f2bf(x2 * c + x1 * sn);
}

// ---------------- bf16 GEMM (m97 structure): C = A[M][K] @ Bt[N][K]^T (+bias) --
template <bool HAS_BIAS, bool OUT_F32>
__global__ __launch_bounds__(256) void gemm_bt(
    const unsigned short* __restrict__ A, const unsigned short* __restrict__ Bt,
    const float* __restrict__ bias, void* __restrict__ Cout, int M, int N, int K) {
  __shared__ unsigned short As[128 * 64];
  __shared__ unsigned short Bs[128 * 64];
  const int tid = threadIdx.x;
  const int wid = tid >> 6, lane = tid & 63;
  const int l16 = lane & 15, lg = lane >> 4;
  const int brow = blockIdx.y * 128, bcol = blockIdx.x * 128;
  const int wr = (wid >> 1) * 64, wc = (wid & 1) * 64;

  f32x4 acc[4][4] = {};
  const int nk = K >> 6;
  for (int kt = 0; kt < nk; ++kt) {
    const int k0 = kt << 6;
#pragma unroll
    for (int it = 0; it < 4; ++it) {
      int e = it * 2048 + wid * 512 + lane * 8;   // element index in 128x64 tile
      int r = e >> 6, c = e & 63;
      gload_lds16(A + (size_t)(brow + r) * K + k0 + c,
                  (char*)As + it * 4096 + wid * 1024);
      gload_lds16(Bt + (size_t)(bcol + r) * K + k0 + c,
                  (char*)Bs + it * 4096 + wid * 1024);
    }
    __syncthreads();
#pragma unroll
    for (int kk = 0; kk < 2; ++kk) {
      short8 a[4], b[4];
#pragma unroll
      for (int m = 0; m < 4; ++m)
        a[m] = *(const short8*)&As[(wr + m * 16 + l16) * 64 + kk * 32 + lg * 8];
#pragma unroll
      for (int n = 0; n < 4; ++n)
        b[n] = *(const short8*)&Bs[(wc + n * 16 + l16) * 64 + kk * 32 + lg * 8];
#pragma unroll
      for (int m = 0; m < 4; ++m)
#pragma unroll
        for (int n = 0; n < 4; ++n)
          acc[m][n] = __builtin_amdgcn_mfma_f32_16x16x32_bf16(a[m], b[n], acc[m][n], 0, 0, 0);
    }
    __syncthreads();
  }
#pragma unroll
  for (int m = 0; m < 4; ++m) {
    int row = brow + wr + m * 16 + lg * 4;
#pragma unroll
    for (int n = 0; n < 4; ++n) {
      int col = bcol + wc + n * 16 + l16;
      float bv = HAS_BIAS ? bias[col] : 0.f;
#pragma unroll
      for (int r = 0; r < 4; ++r) {
        float v = acc[m][n][r] + bv;
        if constexpr (OUT_F32)
          ((float*)Cout)[(size_t)(row + r) * N + col] = v;
        else
          ((unsigned short*)Cout)[(size_t)(row + r) * N + col] = f2bf(v);
      }
    }
  }
}

// ---------------- flash attention (causal, GQA 7:1) ----------------
// 64-row q-tiles, paired (bx, 31-bx) sequentially for perfect causal balance:
// every block does exactly (bx+1)+(32-bx)=33 KV steps.
// grid (16 pairs, 28 heads), 256 threads = 4 waves, wave = 16 q-rows.
__global__ __launch_bounds__(256) void attn(const unsigned short* __restrict__ QKV,
                                            unsigned short* __restrict__ ctx) {
  __shared__ unsigned short Ks[64][136];   // K tile [kv][d], +8 pad (272B rows, 16B-aligned)
  __shared__ unsigned short Vt[128][72];   // V^T tile [d][kv'], kv' XOR-swizzled
  __shared__ unsigned short Ps[4][16][72]; // per-wave P [q][kv'], col XOR-swizzled
  const int tid = threadIdx.x, wid = tid >> 6, lane = tid & 63;
  const int l16 = lane & 15, lg = lane >> 4;
  const int bx = blockIdx.x, h = blockIdx.y;
  const int kvh = h / GROUPS;
  const int koff = HID + kvh * DHEAD, voff = HID + 512 + kvh * DHEAD;
  const float SCALE = 0.08838834764831845f;     // 1/sqrt(128)

  // staging coordinates (coalesced: 16 lanes read 256B of one QKV row)
  const int sr = tid >> 4;           // 0..15 : kv row within 16-row group
  const int sc = (tid & 15) * 8;     // d offset 0..120
  const int vsw = (tid & 7) << 3;    // V swizzle: kv' = kv ^ ((d>>3 & 7)<<3), d>>3 = tid&15

  for (int ph = 0; ph < 2; ++ph) {
    const int tile = ph == 0 ? bx : 31 - bx;   // q-rows [tile*64, tile*64+64)
    const int qrow = tile * 64 + wid * 16;     // this wave's 16 q-rows

    // Q fragments: rows qrow + l16, k = kb*32 + lg*8
    short8 qf[4];
#pragma unroll
    for (int kb = 0; kb < 4; ++kb)
      qf[kb] = *(const short8*)&QKV[(size_t)(qrow + l16) * QKV_N + h * DHEAD + kb * 32 + lg * 8];

    f32x4 of[8] = {};
    float mrun[4], lrun[4];
#pragma unroll
    for (int r = 0; r < 4; ++r) { mrun[r] = -INFINITY; lrun[r] = 0.f; }

    const int nkt = tile + 1;
    for (int kt = 0; kt < nkt; ++kt) {
      // ---- stage K (row-major padded) and V (transposed, kv-swizzled) ----
#pragma unroll
      for (int p = 0; p < 4; ++p) {
        int r = p * 16 + sr;
        size_t grow = (size_t)(kt * 64 + r) * QKV_N;
        uint4 kk = *(const uint4*)&QKV[grow + koff + sc];
        *(uint4*)&Ks[r][sc] = kk;
        uint4 vv = *(const uint4*)&QKV[grow + voff + sc];
        const unsigned short* vs = (const unsigned short*)&vv;
#pragma unroll
        for (int j = 0; j < 8; ++j) Vt[sc + j][r ^ vsw] = vs[j];
      }
      __syncthreads();

      // ---- S = Q K^T ----
      f32x4 s[4] = {};
#pragma unroll
      for (int kb = 0; kb < 4; ++kb) {
        short8 b[4];
#pragma unroll
        for (int cb = 0; cb < 4; ++cb)
          b[cb] = *(const short8*)&Ks[cb * 16 + l16][kb * 32 + lg * 8];
#pragma unroll
        for (int cb = 0; cb < 4; ++cb)
          s[cb] = __builtin_amdgcn_mfma_f32_16x16x32_bf16(qf[kb], b[cb], s[cb], 0, 0, 0);
      }

      // ---- online softmax (mask only on the diagonal step) ----
      const bool diag = (kt == tile);
      float rmax[4], rsum[4], mnew[4], alpha[4];
#pragma unroll
      for (int r = 0; r < 4; ++r) rmax[r] = -INFINITY;
#pragma unroll
      for (int cb = 0; cb < 4; ++cb)
#pragma unroll
        for (int r = 0; r < 4; ++r) {
          float v = s[cb][r] * SCALE;
          if (diag) {
            int qg = wid * 16 + lg * 4 + r;       // within-tile row
            int kg = cb * 16 + l16;               // within-tile kv
            if (kg > qg) v = -1e30f;
          }
          s[cb][r] = v;
          rmax[r] = fmaxf(rmax[r], v);
        }
#pragma unroll
      for (int r = 0; r < 4; ++r) {
#pragma unroll
        for (int msk = 1; msk < 16; msk <<= 1)
          rmax[r] = fmaxf(rmax[r], __shfl_xor(rmax[r], msk, 64));
        mnew[r] = fmaxf(mrun[r], rmax[r]);
        alpha[r] = __expf(mrun[r] - mnew[r]);
        rsum[r] = 0.f;
      }
#pragma unroll
      for (int cb = 0; cb < 4; ++cb)
#pragma unroll
        for (int r = 0; r < 4; ++r) {
          float p = __expf(s[cb][r] - mnew[r]);
          s[cb][r] = p;
          rsum[r] += p;
        }
#pragma unroll
      for (int r = 0; r < 4; ++r) {
#pragma unroll
        for (int msk = 1; msk < 16; msk <<= 1)
          rsum[r] += __shfl_xor(rsum[r], msk, 64);
        lrun[r] = lrun[r] * alpha[r] + rsum[r];
        mrun[r] = mnew[r];
      }
#pragma unroll
      for (int nb = 0; nb < 8; ++nb)
#pragma unroll
        for (int r = 0; r < 4; ++r) of[nb][r] *= alpha[r];
      // C-frag -> LDS (A-frag re-layout); col' = col ^ ((row>>2 & 3)<<4), row>>2 = lg
      {
        const int psw = lg << 4;
#pragma unroll
        for (int cb = 0; cb < 4; ++cb)
#pragma unroll
          for (int r = 0; r < 4; ++r)
            Ps[wid][lg * 4 + r][(cb * 16 + l16) ^ psw] = f2bf(s[cb][r]);
      }

      // ---- PV ----
#pragma unroll
      for (int kb = 0; kb < 2; ++kb) {
        short8 pa = *(const short8*)&Ps[wid][l16][(kb * 32 + lg * 8) ^ ((l16 >> 2) << 4)];
#pragma unroll
        for (int nb = 0; nb < 8; ++nb) {
          int vrow = nb * 16 + l16;
          int vcol = (kb * 32 + lg * 8) ^ (((vrow >> 3) & 7) << 3);
          short8 vb = *(const short8*)&Vt[vrow][vcol];
          of[nb] = __builtin_amdgcn_mfma_f32_16x16x32_bf16(pa, vb, of[nb], 0, 0, 0);
        }
      }
      __syncthreads();
    }

    // ---- epilogue: ctx[s][h*128+d] ----
#pragma unroll
    for (int r = 0; r < 4; ++r) {
      float inv = 1.f / lrun[r];
      int row = qrow + lg * 4 + r;
#pragma unroll
      for (int nb = 0; nb < 8; ++nb)
        ctx[(size_t)row * HID + h * DHEAD + nb * 16 + l16] = f2bf(of[nb][r] * inv);
    }
  }
}

// ---------------- host launch ----------------
extern "C" void kernel_launch(void* const* d_in, const int* in_sizes, int n_in,
                              void* d_out, int out_size, void* d_ws, size_t ws_size,
                              hipStream_t stream) {
  (void)in_sizes; (void)n_in; (void)out_size; (void)ws_size;
  const float* X   = (const float*)d_in[0];
  const int*   pos = (const int*)d_in[1];
  const float* qw  = (const float*)d_in[2];
  const float* qb  = (const float*)d_in[3];
  const float* kw  = (const float*)d_in[4];
  const float* kb  = (const float*)d_in[5];
  const float* vw  = (const float*)d_in[6];
  const float* vb  = (const float*)d_in[7];
  const float* ow  = (const float*)d_in[8];
  float* out = (float*)d_out;

  char* w = (char*)d_ws;
  unsigned short* Xb    = (unsigned short*)w; w += (size_t)S_LEN * HID * 2;
  unsigned short* Wqkvt = (unsigned short*)w; w += (size_t)QKV_N * HID * 2;
  unsigned short* Wot   = (unsigned short*)w; w += (size_t)HID * HID * 2;
  float*          bqkv  = (float*)w;          w += (size_t)QKV_N * 4;
  unsigned short* QKV   = (unsigned short*)w; w += (size_t)S_LEN * QKV_N * 2;
  float*          ct    = (float*)w;          w += (size_t)S_LEN * 64 * 4;
  float*          st    = (float*)w;          w += (size_t)S_LEN * 64 * 4;
  unsigned short* ctx   = (unsigned short*)w; w += (size_t)S_LEN * HID * 2;

  conv_f32_bf16<<<2048, 256, 0, stream>>>(X, Xb, S_LEN * HID);
  transpose_conv<<<dim3(112, 112), dim3(32, 8), 0, stream>>>(qw, Wqkvt, HID, HID);
  transpose_conv<<<dim3(16, 112),  dim3(32, 8), 0, stream>>>(kw, Wqkvt + (size_t)HID * HID, HID, 512);
  transpose_conv<<<dim3(16, 112),  dim3(32, 8), 0, stream>>>(vw, Wqkvt + (size_t)(HID + 512) * HID, HID, 512);
  transpose_conv<<<dim3(112, 112), dim3(32, 8), 0, stream>>>(ow, Wot, HID, HID);
  concat_bias<<<18, 256, 0, stream>>>(qb, kb, vb, bqkv);
  rope_table<<<S_LEN, 64, 0, stream>>>(pos, ct, st);

  gemm_bt<true, false><<<dim3(QKV_N / 128, S_LEN / 128), 256, 0, stream>>>(
      Xb, Wqkvt, bqkv, QKV, S_LEN, QKV_N, HID);
  rope_apply<<<(S_LEN * 32 * 64) / 256, 256, 0, stream>>>(QKV, ct, st);
  attn<<<dim3(16, NH), 256, 0, stream>>>(QKV, ctx);
  gemm_bt<false, true><<<dim3(HID / 128, S_LEN / 128), 256, 0, stream>>>(
      ctx, Wot, nullptr, out, S_LEN, HID, HID);
}

// Round 3
// 538.845 us; speedup vs baseline: 1.2587x; 1.0864x over previous
//
#include <hip/hip_runtime.h>
#include <cstdint>
#include <cstddef>

// ---------------- problem constants ----------------
#define S_LEN 2048
#define HID   3584
#define NH    28
#define NKV   4
#define DHEAD 128
#define QKV_N 4608   /* 3584 Q + 512 K + 512 V */
#define GROUPS 7

typedef __attribute__((ext_vector_type(8))) short  short8;   // 8 bf16 (4 VGPRs)
typedef __attribute__((ext_vector_type(4))) float  f32x4;    // MFMA accumulator

__device__ __forceinline__ unsigned short f2bf(float f) {
  unsigned int u = __builtin_bit_cast(unsigned int, f);
  u += 0x7FFFu + ((u >> 16) & 1u);            // RNE
  return (unsigned short)(u >> 16);
}
__device__ __forceinline__ float bf2f(unsigned short b) {
  unsigned int u = ((unsigned int)b) << 16;
  return __builtin_bit_cast(float, u);
}
// async global->LDS, 16B/lane. lds ptr must be wave-uniform; HW adds lane*16.
__device__ __forceinline__ void gload_lds16(const void* g, void* l) {
  __builtin_amdgcn_global_load_lds(
      (const __attribute__((address_space(1))) unsigned int*)g,
      (__attribute__((address_space(3))) unsigned int*)l, 16, 0, 0);
}

// ---------------- fp32 -> bf16 elementwise convert ----------------
__global__ void conv_f32_bf16(const float* __restrict__ in,
                              unsigned short* __restrict__ out, int n) {
  int i = (blockIdx.x * blockDim.x + threadIdx.x) * 4;
  int stride = gridDim.x * blockDim.x * 4;
  for (; i < n; i += stride) {
    float4 v = *(const float4*)&in[i];
    ushort4 o;
    o.x = f2bf(v.x); o.y = f2bf(v.y); o.z = f2bf(v.z); o.w = f2bf(v.w);
    *(ushort4*)&out[i] = o;
  }
}

// ---------------- transpose + convert: W[K][N] f32 -> Wt[N][K] bf16 ----------
__global__ void transpose_conv(const float* __restrict__ W,
                               unsigned short* __restrict__ Wt, int K, int N) {
  __shared__ float tile[32][33];
  int n0 = blockIdx.x * 32, k0 = blockIdx.y * 32;
  int tx = threadIdx.x, ty = threadIdx.y;          // block (32,8)
#pragma unroll
  for (int i = 0; i < 4; ++i)
    tile[ty + i * 8][tx] = W[(size_t)(k0 + ty + i * 8) * N + n0 + tx];
  __syncthreads();
#pragma unroll
  for (int i = 0; i < 4; ++i)
    Wt[(size_t)(n0 + ty + i * 8) * K + k0 + tx] = f2bf(tile[tx][ty + i * 8]);
}

// ---------------- bias concat [q_b | k_b | v_b] -> fp32[4608] ----------------
__global__ void concat_bias(const float* __restrict__ qb, const float* __restrict__ kb,
                            const float* __restrict__ vb, float* __restrict__ out) {
  int i = blockIdx.x * blockDim.x + threadIdx.x;
  if (i < HID) out[i] = qb[i];
  else if (i < HID + 512) out[i] = kb[i - HID];
  else if (i < QKV_N) out[i] = vb[i - HID - 512];
}

// ---------------- RoPE cos/sin table: [2048][64] each ----------------
__global__ void rope_table(const int* __restrict__ pos, float* __restrict__ ct,
                           float* __restrict__ st) {
  int p = blockIdx.x, i = threadIdx.x;            // 64 threads
  float pf = (float)pos[p];
  float inv = __expf(-(float)i * (13.815510557964274f / 64.0f));
  float f = pf * inv;
  ct[p * 64 + i] = cosf(f);
  st[p * 64 + i] = sinf(f);
}

// ---------------- RoPE apply in-place on Q,K halves of QKV ----------------
__global__ void rope_apply(unsigned short* __restrict__ QKV,
                           const float* __restrict__ ct, const float* __restrict__ st) {
  int idx = blockIdx.x * blockDim.x + threadIdx.x;  // 2048 * 32 * 64 total
  int i  = idx & 63;
  int hs = (idx >> 6) & 31;                         // 0..27 Q heads, 28..31 K heads
  int s  = idx >> 11;
  int cb = hs < NH ? hs * DHEAD : HID + (hs - NH) * DHEAD;
  size_t base = (size_t)s * QKV_N + cb;
  float x1 = bf2f(QKV[base + i]);
  float x2 = bf2f(QKV[base + 64 + i]);
  float c = ct[s * 64 + i], sn = st[s * 64 + i];
  QKV[base + i]      = f2bf(x1 * c - x2 * sn);
  QKV[base + 64 + i] = f2bf(x2 * c + x1 * sn);
}

// ================= 256x256 8-phase bf16 GEMM (m201 template port) =============
// C[M][N] = A[M][K] @ Bt[N][K]^T (+bias). 512 threads = 8 waves (2M x 4N).
// LDS: 2-deep double buffer, A/B tiles 256x64 bf16, granule-swizzled
// (cb' = cb ^ (row&7)) via pre-swizzled global source + linear LDS dest.
// Per tile: 4 phases, counted vmcnt(4) once per tile (never 0 in loop).
__device__ __forceinline__ void stage_half(const unsigned short* g, int K,
                                           unsigned short* lds, int tid, int wid,
                                           int cbs) {
  // g points at (row0, k0) of a 128-row x 64-col half-panel.
#pragma unroll
  for (int i = 0; i < 2; ++i) {
    int row = (i * 512 + tid) >> 3;
    gload_lds16(g + (size_t)row * K + cbs * 8,
                (char*)lds + (size_t)(i * 512 + wid * 64) * 16);
  }
}

#define MFMA_BF16(a, b, c) __builtin_amdgcn_mfma_f32_16x16x32_bf16((a), (b), (c), 0, 0, 0)

template <bool HAS_BIAS, bool OUT_F32>
__global__ __launch_bounds__(512, 2) void gemm256(
    const unsigned short* __restrict__ A, const unsigned short* __restrict__ Bt,
    const float* __restrict__ bias, void* __restrict__ Cout, int M, int N, int K) {
  __shared__ unsigned short As[2][16384];   // [buf][256 rows x 64 k], swizzled granules
  __shared__ unsigned short Bs[2][16384];
  const int tid = threadIdx.x, wid = tid >> 6, lane = tid & 63;
  const int l16 = lane & 15, lg = lane >> 4;
  const int wm = wid >> 2, wn = wid & 3;
  const int brow = blockIdx.y * 256, bcol = blockIdx.x * 256;
  // staging: physical granule tid%8 holds logical cb = (tid&7)^((tid>>3)&7)
  const int cbs = (tid & 7) ^ ((tid >> 3) & 7);
  // reading: row % 8 == l16 % 8 for all fragment rows -> per-lane constant cols
  const int ca0 = ((0 + lg) ^ (l16 & 7)) * 8;   // ks=0 granule col (elements)
  const int ca1 = ((4 + lg) ^ (l16 & 7)) * 8;   // ks=1

  const unsigned short* Ag = A + (size_t)brow * K;
  const unsigned short* Bg = Bt + (size_t)bcol * K;

  f32x4 acc[8][4] = {};
  const int nt = K >> 6;

  // ---- prologue: tile0 all 4 halves + tile1 {A0,B0} ----
  stage_half(Ag,                    K, &As[0][0],    tid, wid, cbs);  // t0 A0
  stage_half(Ag + (size_t)128 * K,  K, &As[0][8192], tid, wid, cbs);  // t0 A1
  stage_half(Bg,                    K, &Bs[0][0],    tid, wid, cbs);  // t0 B0
  stage_half(Bg + (size_t)128 * K,  K, &Bs[0][8192], tid, wid, cbs);  // t0 B1
  stage_half(Ag + 64,               K, &As[1][0],    tid, wid, cbs);  // t1 A0
  stage_half(Bg + 64,               K, &Bs[1][0],    tid, wid, cbs);  // t1 B0
  asm volatile("s_waitcnt vmcnt(4)" ::: "memory");   // t0 fully landed
  __builtin_amdgcn_s_barrier();
  __builtin_amdgcn_sched_barrier(0);

  for (int t = 0; t < nt; ++t) {
    unsigned short* Ac = As[t & 1];
    unsigned short* Bc = Bs[t & 1];
    unsigned short* An = As[(t & 1) ^ 1];
    unsigned short* Bn = Bs[(t & 1) ^ 1];
    const int k1 = (t + 1) << 6, k2 = (t + 2) << 6;
    const bool st1 = (t + 1) < nt, st2 = (t + 2) < nt;
    short8 af[4][2], bf[4][2];

    // ===== phase 0: quadrant (A0,B0) -> acc[0..3][0..1] =====
#pragma unroll
    for (int mi = 0; mi < 4; ++mi) {
      int rb = (wm * 64 + mi * 16 + l16) * 64;
      af[mi][0] = *(const short8*)&Ac[rb + ca0];
      af[mi][1] = *(const short8*)&Ac[rb + ca1];
    }
#pragma unroll
    for (int ni = 0; ni < 2; ++ni) {
      int rb = (wn * 32 + ni * 16 + l16) * 64;
      bf[ni][0] = *(const short8*)&Bc[rb + ca0];
      bf[ni][1] = *(const short8*)&Bc[rb + ca1];
    }
    if (st1) stage_half(Ag + (size_t)128 * K + k1, K, An + 8192, tid, wid, cbs);
    __builtin_amdgcn_sched_barrier(0);
    __builtin_amdgcn_s_barrier();
    __builtin_amdgcn_sched_barrier(0);
    __builtin_amdgcn_s_setprio(1);
#pragma unroll
    for (int mi = 0; mi < 4; ++mi)
#pragma unroll
      for (int ni = 0; ni < 2; ++ni) {
        acc[mi][ni] = MFMA_BF16(af[mi][0], bf[ni][0], acc[mi][ni]);
        acc[mi][ni] = MFMA_BF16(af[mi][1], bf[ni][1], acc[mi][ni]);
      }
    __builtin_amdgcn_s_setprio(0);
    __builtin_amdgcn_sched_barrier(0);
    __builtin_amdgcn_s_barrier();
    __builtin_amdgcn_sched_barrier(0);

    // ===== phase 1: quadrant (A0,B1) -> acc[0..3][2..3]  (af reused) =====
#pragma unroll
    for (int ni = 0; ni < 2; ++ni) {
      int rb = (wn * 32 + ni * 16 + l16) * 64;
      bf[2 + ni][0] = *(const short8*)&Bc[8192 + rb + ca0];
      bf[2 + ni][1] = *(const short8*)&Bc[8192 + rb + ca1];
    }
    if (st1) stage_half(Bg + (size_t)128 * K + k1, K, Bn + 8192, tid, wid, cbs);
    __builtin_amdgcn_sched_barrier(0);
    __builtin_amdgcn_s_barrier();
    __builtin_amdgcn_sched_barrier(0);
    __builtin_amdgcn_s_setprio(1);
#pragma unroll
    for (int mi = 0; mi < 4; ++mi)
#pragma unroll
      for (int ni = 0; ni < 2; ++ni) {
        acc[mi][2 + ni] = MFMA_BF16(af[mi][0], bf[2 + ni][0], acc[mi][2 + ni]);
        acc[mi][2 + ni] = MFMA_BF16(af[mi][1], bf[2 + ni][1], acc[mi][2 + ni]);
      }
    __builtin_amdgcn_s_setprio(0);
    __builtin_amdgcn_sched_barrier(0);
    __builtin_amdgcn_s_barrier();
    __builtin_amdgcn_sched_barrier(0);

    // ===== phase 2: quadrant (A1,B0) -> acc[4..7][0..1]  (bf[0..1] reused) =====
#pragma unroll
    for (int mi = 0; mi < 4; ++mi) {
      int rb = (wm * 64 + mi * 16 + l16) * 64;
      af[mi][0] = *(const short8*)&Ac[8192 + rb + ca0];
      af[mi][1] = *(const short8*)&Ac[8192 + rb + ca1];
    }
    if (st2) stage_half(Ag + k2, K, Ac, tid, wid, cbs);   // A0 of t+2 (last read: ph0)
    __builtin_amdgcn_sched_barrier(0);
    __builtin_amdgcn_s_barrier();
    __builtin_amdgcn_sched_barrier(0);
    __builtin_amdgcn_s_setprio(1);
#pragma unroll
    for (int mi = 0; mi < 4; ++mi)
#pragma unroll
      for (int ni = 0; ni < 2; ++ni) {
        acc[4 + mi][ni] = MFMA_BF16(af[mi][0], bf[ni][0], acc[4 + mi][ni]);
        acc[4 + mi][ni] = MFMA_BF16(af[mi][1], bf[ni][1], acc[4 + mi][ni]);
      }
    __builtin_amdgcn_s_setprio(0);
    __builtin_amdgcn_sched_barrier(0);
    __builtin_amdgcn_s_barrier();
    __builtin_amdgcn_sched_barrier(0);

    // ===== phase 3: quadrant (A1,B1) -> acc[4..7][2..3]  (no new reads) =====
    if (st2) stage_half(Bg + k2, K, Bc, tid, wid, cbs);   // B0 of t+2 (last read: ph0)
    __builtin_amdgcn_sched_barrier(0);
    __builtin_amdgcn_s_barrier();
    __builtin_amdgcn_sched_barrier(0);
    __builtin_amdgcn_s_setprio(1);
#pragma unroll
    for (int mi = 0; mi < 4; ++mi)
#pragma unroll
      for (int ni = 0; ni < 2; ++ni) {
        acc[4 + mi][2 + ni] = MFMA_BF16(af[mi][0], bf[2 + ni][0], acc[4 + mi][2 + ni]);
        acc[4 + mi][2 + ni] = MFMA_BF16(af[mi][1], bf[2 + ni][1], acc[4 + mi][2 + ni]);
      }
    __builtin_amdgcn_s_setprio(0);
    // counted wait: leave t+2:{A0,B0} (4 loads) in flight; t+1 fully landed
    asm volatile("s_waitcnt vmcnt(4)" ::: "memory");
    __builtin_amdgcn_sched_barrier(0);
    __builtin_amdgcn_s_barrier();
    __builtin_amdgcn_sched_barrier(0);
  }

  // ---- epilogue ----
#pragma unroll
  for (int mf = 0; mf < 8; ++mf) {
    int row = brow + (mf >> 2) * 128 + wm * 64 + (mf & 3) * 16 + lg * 4;
#pragma unroll
    for (int nf = 0; nf < 4; ++nf) {
      int col = bcol + (nf >> 1) * 128 + wn * 32 + (nf & 1) * 16 + l16;
      float bv = HAS_BIAS ? bias[col] : 0.f;
#pragma unroll
      for (int r = 0; r < 4; ++r) {
        float v = acc[mf][nf][r] + bv;
        if constexpr (OUT_F32)
          ((float*)Cout)[(size_t)(row + r) * N + col] = v;
        else
          ((unsigned short*)Cout)[(size_t)(row + r) * N + col] = f2bf(v);
      }
    }
  }
}

// ---------------- flash attention (causal, GQA 7:1) ----------------
// 64-row q-tiles, paired (bx, 31-bx) sequentially for perfect causal balance.
__global__ __launch_bounds__(256) void attn(const unsigned short* __restrict__ QKV,
                                            unsigned short* __restrict__ ctx) {
  __shared__ unsigned short Ks[64][136];   // K tile [kv][d], padded
  __shared__ unsigned short Vt[128][72];   // V^T tile [d][kv'], kv' XOR-swizzled
  __shared__ unsigned short Ps[4][16][72]; // per-wave P [q][kv'], col XOR-swizzled
  const int tid = threadIdx.x, wid = tid >> 6, lane = tid & 63;
  const int l16 = lane & 15, lg = lane >> 4;
  const int bx = blockIdx.x, h = blockIdx.y;
  const int kvh = h / GROUPS;
  const int koff = HID + kvh * DHEAD, voff = HID + 512 + kvh * DHEAD;
  const float SCALE = 0.08838834764831845f;     // 1/sqrt(128)

  const int sr = tid >> 4;           // 0..15 : kv row within 16-row group
  const int sc = (tid & 15) * 8;     // d offset 0..120
  const int vsw = (tid & 7) << 3;    // V swizzle: kv' = kv ^ ((d>>3 & 7)<<3)

  for (int ph = 0; ph < 2; ++ph) {
    const int tile = ph == 0 ? bx : 31 - bx;   // q-rows [tile*64, tile*64+64)
    const int qrow = tile * 64 + wid * 16;     // this wave's 16 q-rows

    short8 qf[4];
#pragma unroll
    for (int kb = 0; kb < 4; ++kb)
      qf[kb] = *(const short8*)&QKV[(size_t)(qrow + l16) * QKV_N + h * DHEAD + kb * 32 + lg * 8];

    f32x4 of[8] = {};
    float mrun[4], lrun[4];
#pragma unroll
    for (int r = 0; r < 4; ++r) { mrun[r] = -INFINITY; lrun[r] = 0.f; }

    const int nkt = tile + 1;
    for (int kt = 0; kt < nkt; ++kt) {
      // ---- stage K (row-major padded) and V (transposed, kv-swizzled) ----
#pragma unroll
      for (int p = 0; p < 4; ++p) {
        int r = p * 16 + sr;
        size_t grow = (size_t)(kt * 64 + r) * QKV_N;
        uint4 kk = *(const uint4*)&QKV[grow + koff + sc];
        *(uint4*)&Ks[r][sc] = kk;
        uint4 vv = *(const uint4*)&QKV[grow + voff + sc];
        const unsigned short* vs = (const unsigned short*)&vv;
#pragma unroll
        for (int j = 0; j < 8; ++j) Vt[sc + j][r ^ vsw] = vs[j];
      }
      __syncthreads();

      // ---- S = Q K^T ----
      f32x4 s[4] = {};
#pragma unroll
      for (int kb = 0; kb < 4; ++kb) {
        short8 b[4];
#pragma unroll
        for (int cb = 0; cb < 4; ++cb)
          b[cb] = *(const short8*)&Ks[cb * 16 + l16][kb * 32 + lg * 8];
#pragma unroll
        for (int cb = 0; cb < 4; ++cb)
          s[cb] = MFMA_BF16(qf[kb], b[cb], s[cb]);
      }

      // ---- online softmax (mask only on the diagonal step) ----
      const bool diag = (kt == tile);
      float rmax[4], rsum[4], mnew[4], alpha[4];
#pragma unroll
      for (int r = 0; r < 4; ++r) rmax[r] = -INFINITY;
#pragma unroll
      for (int cb = 0; cb < 4; ++cb)
#pragma unroll
        for (int r = 0; r < 4; ++r) {
          float v = s[cb][r] * SCALE;
          if (diag) {
            int qg = wid * 16 + lg * 4 + r;
            int kg = cb * 16 + l16;
            if (kg > qg) v = -1e30f;
          }
          s[cb][r] = v;
          rmax[r] = fmaxf(rmax[r], v);
        }
#pragma unroll
      for (int r = 0; r < 4; ++r) {
#pragma unroll
        for (int msk = 1; msk < 16; msk <<= 1)
          rmax[r] = fmaxf(rmax[r], __shfl_xor(rmax[r], msk, 64));
        mnew[r] = fmaxf(mrun[r], rmax[r]);
        alpha[r] = __expf(mrun[r] - mnew[r]);
        rsum[r] = 0.f;
      }
#pragma unroll
      for (int cb = 0; cb < 4; ++cb)
#pragma unroll
        for (int r = 0; r < 4; ++r) {
          float p = __expf(s[cb][r] - mnew[r]);
          s[cb][r] = p;
          rsum[r] += p;
        }
#pragma unroll
      for (int r = 0; r < 4; ++r) {
#pragma unroll
        for (int msk = 1; msk < 16; msk <<= 1)
          rsum[r] += __shfl_xor(rsum[r], msk, 64);
        lrun[r] = lrun[r] * alpha[r] + rsum[r];
        mrun[r] = mnew[r];
      }
#pragma unroll
      for (int nb = 0; nb < 8; ++nb)
#pragma unroll
        for (int r = 0; r < 4; ++r) of[nb][r] *= alpha[r];
      {
        const int psw = lg << 4;
#pragma unroll
        for (int cb = 0; cb < 4; ++cb)
#pragma unroll
          for (int r = 0; r < 4; ++r)
            Ps[wid][lg * 4 + r][(cb * 16 + l16) ^ psw] = f2bf(s[cb][r]);
      }

      // ---- PV ----
#pragma unroll
      for (int kb = 0; kb < 2; ++kb) {
        short8 pa = *(const short8*)&Ps[wid][l16][(kb * 32 + lg * 8) ^ ((l16 >> 2) << 4)];
#pragma unroll
        for (int nb = 0; nb < 8; ++nb) {
          int vrow = nb * 16 + l16;
          int vcol = (kb * 32 + lg * 8) ^ (((vrow >> 3) & 7) << 3);
          short8 vb = *(const short8*)&Vt[vrow][vcol];
          of[nb] = MFMA_BF16(pa, vb, of[nb]);
        }
      }
      __syncthreads();
    }

    // ---- epilogue: ctx[s][h*128+d] ----
#pragma unroll
    for (int r = 0; r < 4; ++r) {
      float inv = 1.f / lrun[r];
      int row = qrow + lg * 4 + r;
#pragma unroll
      for (int nb = 0; nb < 8; ++nb)
        ctx[(size_t)row * HID + h * DHEAD + nb * 16 + l16] = f2bf(of[nb][r] * inv);
    }
  }
}

// ---------------- host launch ----------------
extern "C" void kernel_launch(void* const* d_in, const int* in_sizes, int n_in,
                              void* d_out, int out_size, void* d_ws, size_t ws_size,
                              hipStream_t stream) {
  (void)in_sizes; (void)n_in; (void)out_size; (void)ws_size;
  const float* X   = (const float*)d_in[0];
  const int*   pos = (const int*)d_in[1];
  const float* qw  = (const float*)d_in[2];
  const float* qb  = (const float*)d_in[3];
  const float* kw  = (const float*)d_in[4];
  const float* kb  = (const float*)d_in[5];
  const float* vw  = (const float*)d_in[6];
  const float* vb  = (const float*)d_in[7];
  const float* ow  = (const float*)d_in[8];
  float* out = (float*)d_out;

  char* w = (char*)d_ws;
  unsigned short* Xb    = (unsigned short*)w; w += (size_t)S_LEN * HID * 2;
  unsigned short* Wqkvt = (unsigned short*)w; w += (size_t)QKV_N * HID * 2;
  unsigned short* Wot   = (unsigned short*)w; w += (size_t)HID * HID * 2;
  float*          bqkv  = (float*)w;          w += (size_t)QKV_N * 4;
  unsigned short* QKV   = (unsigned short*)w; w += (size_t)S_LEN * QKV_N * 2;
  float*          ct    = (float*)w;          w += (size_t)S_LEN * 64 * 4;
  float*          st    = (float*)w;          w += (size_t)S_LEN * 64 * 4;
  unsigned short* ctx   = (unsigned short*)w; w += (size_t)S_LEN * HID * 2;

  conv_f32_bf16<<<2048, 256, 0, stream>>>(X, Xb, S_LEN * HID);
  transpose_conv<<<dim3(112, 112), dim3(32, 8), 0, stream>>>(qw, Wqkvt, HID, HID);
  transpose_conv<<<dim3(16, 112),  dim3(32, 8), 0, stream>>>(kw, Wqkvt + (size_t)HID * HID, HID, 512);
  transpose_conv<<<dim3(16, 112),  dim3(32, 8), 0, stream>>>(vw, Wqkvt + (size_t)(HID + 512) * HID, HID, 512);
  transpose_conv<<<dim3(112, 112), dim3(32, 8), 0, stream>>>(ow, Wot, HID, HID);
  concat_bias<<<18, 256, 0, stream>>>(qb, kb, vb, bqkv);
  rope_table<<<S_LEN, 64, 0, stream>>>(pos, ct, st);

  gemm256<true, false><<<dim3(QKV_N / 256, S_LEN / 256), 512, 0, stream>>>(
      Xb, Wqkvt, bqkv, QKV, S_LEN, QKV_N, HID);
  rope_apply<<<(S_LEN * 32 * 64) / 256, 256, 0, stream>>>(QKV, ct, st);
  attn<<<dim3(16, NH), 256, 0, stream>>>(QKV, ctx);
  gemm256<false, true><<<dim3(HID / 256, S_LEN / 256), 512, 0, stream>>>(
      ctx, Wot, nullptr, out, S_LEN, HID, HID);
}

// Round 4
// 472.440 us; speedup vs baseline: 1.4356x; 1.1406x over previous
//
#include <hip/hip_runtime.h>
#include <cstdint>
#include <cstddef>

// ---------------- problem constants ----------------
#define S_LEN 2048
#define HID   3584
#define NH    28
#define NKV   4
#define DHEAD 128
#define QKV_N 4608   /* 3584 Q + 512 K + 512 V */
#define GROUPS 7

typedef __attribute__((ext_vector_type(8))) short  short8;   // 8 bf16 (4 VGPRs)
typedef __attribute__((ext_vector_type(4))) float  f32x4;    // MFMA accumulator

__device__ __forceinline__ unsigned short f2bf(float f) {
  unsigned int u = __builtin_bit_cast(unsigned int, f);
  u += 0x7FFFu + ((u >> 16) & 1u);            // RNE
  return (unsigned short)(u >> 16);
}
__device__ __forceinline__ float bf2f(unsigned short b) {
  unsigned int u = ((unsigned int)b) << 16;
  return __builtin_bit_cast(float, u);
}
// async global->LDS, 16B/lane. lds ptr must be wave-uniform; HW adds lane*16.
__device__ __forceinline__ void gload_lds16(const void* g, void* l) {
  __builtin_amdgcn_global_load_lds(
      (const __attribute__((address_space(1))) unsigned int*)g,
      (__attribute__((address_space(3))) unsigned int*)l, 16, 0, 0);
}

#define MFMA_BF16(a, b, c) __builtin_amdgcn_mfma_f32_16x16x32_bf16((a), (b), (c), 0, 0, 0)

// ---------------- fp32 -> bf16 elementwise convert ----------------
__global__ void conv_f32_bf16(const float* __restrict__ in,
                              unsigned short* __restrict__ out, int n) {
  int i = (blockIdx.x * blockDim.x + threadIdx.x) * 4;
  int stride = gridDim.x * blockDim.x * 4;
  for (; i < n; i += stride) {
    float4 v = *(const float4*)&in[i];
    ushort4 o;
    o.x = f2bf(v.x); o.y = f2bf(v.y); o.z = f2bf(v.z); o.w = f2bf(v.w);
    *(ushort4*)&out[i] = o;
  }
}

// ---------------- transpose + convert: W[K][N] f32 -> Wt[N][K] bf16 ----------
__global__ void transpose_conv(const float* __restrict__ W,
                               unsigned short* __restrict__ Wt, int K, int N) {
  __shared__ float tile[32][33];
  int n0 = blockIdx.x * 32, k0 = blockIdx.y * 32;
  int tx = threadIdx.x, ty = threadIdx.y;          // block (32,8)
#pragma unroll
  for (int i = 0; i < 4; ++i)
    tile[ty + i * 8][tx] = W[(size_t)(k0 + ty + i * 8) * N + n0 + tx];
  __syncthreads();
#pragma unroll
  for (int i = 0; i < 4; ++i)
    Wt[(size_t)(n0 + ty + i * 8) * K + k0 + tx] = f2bf(tile[tx][ty + i * 8]);
}

// ---------------- bias concat [q_b | k_b | v_b] -> fp32[4608] ----------------
__global__ void concat_bias(const float* __restrict__ qb, const float* __restrict__ kb,
                            const float* __restrict__ vb, float* __restrict__ out) {
  int i = blockIdx.x * blockDim.x + threadIdx.x;
  if (i < HID) out[i] = qb[i];
  else if (i < HID + 512) out[i] = kb[i - HID];
  else if (i < QKV_N) out[i] = vb[i - HID - 512];
}

// ---------------- RoPE cos/sin table: [2048][64] each ----------------
__global__ void rope_table(const int* __restrict__ pos, float* __restrict__ ct,
                           float* __restrict__ st) {
  int p = blockIdx.x, i = threadIdx.x;            // 64 threads
  float pf = (float)pos[p];
  float inv = __expf(-(float)i * (13.815510557964274f / 64.0f));
  float f = pf * inv;
  ct[p * 64 + i] = cosf(f);
  st[p * 64 + i] = sinf(f);
}

// ---------------- RoPE apply in-place on Q,K halves of QKV ----------------
__global__ void rope_apply(unsigned short* __restrict__ QKV,
                           const float* __restrict__ ct, const float* __restrict__ st) {
  int idx = blockIdx.x * blockDim.x + threadIdx.x;  // 2048 * 32 * 64 total
  int i  = idx & 63;
  int hs = (idx >> 6) & 31;                         // 0..27 Q heads, 28..31 K heads
  int s  = idx >> 11;
  int cb = hs < NH ? hs * DHEAD : HID + (hs - NH) * DHEAD;
  size_t base = (size_t)s * QKV_N + cb;
  float x1 = bf2f(QKV[base + i]);
  float x2 = bf2f(QKV[base + 64 + i]);
  float c = ct[s * 64 + i], sn = st[s * 64 + i];
  QKV[base + i]      = f2bf(x1 * c - x2 * sn);
  QKV[base + 64 + i] = f2bf(x2 * c + x1 * sn);
}

// ================= 256x256 8-phase bf16 GEMM (m201 template port) =============
// C[M][N] = A[M][K] @ Bt[N][K]^T (+bias). 512 threads = 8 waves (2M x 4N).
// SPLIT_V: cols >= 4096 (the V projection) are written TRANSPOSED to
// VtOut[vh][d][s] instead of Cout, so attention can read V^T directly.
__device__ __forceinline__ void stage_half(const unsigned short* g, int K,
                                           unsigned short* lds, int tid, int wid,
                                           int cbs) {
#pragma unroll
  for (int i = 0; i < 2; ++i) {
    int row = (i * 512 + tid) >> 3;
    gload_lds16(g + (size_t)row * K + cbs * 8,
                (char*)lds + (size_t)(i * 512 + wid * 64) * 16);
  }
}

template <bool HAS_BIAS, bool OUT_F32, bool SPLIT_V>
__global__ __launch_bounds__(512, 2) void gemm256(
    const unsigned short* __restrict__ A, const unsigned short* __restrict__ Bt,
    const float* __restrict__ bias, void* __restrict__ Cout,
    unsigned short* __restrict__ VtOut, int M, int N, int K) {
  __shared__ unsigned short As[2][16384];   // [buf][256 rows x 64 k], swizzled granules
  __shared__ unsigned short Bs[2][16384];
  const int tid = threadIdx.x, wid = tid >> 6, lane = tid & 63;
  const int l16 = lane & 15, lg = lane >> 4;
  const int wm = wid >> 2, wn = wid & 3;
  const int brow = blockIdx.y * 256, bcol = blockIdx.x * 256;
  const int cbs = (tid & 7) ^ ((tid >> 3) & 7);
  const int ca0 = ((0 + lg) ^ (l16 & 7)) * 8;   // ks=0 granule col (elements)
  const int ca1 = ((4 + lg) ^ (l16 & 7)) * 8;   // ks=1

  const unsigned short* Ag = A + (size_t)brow * K;
  const unsigned short* Bg = Bt + (size_t)bcol * K;

  f32x4 acc[8][4] = {};
  const int nt = K >> 6;

  stage_half(Ag,                    K, &As[0][0],    tid, wid, cbs);  // t0 A0
  stage_half(Ag + (size_t)128 * K,  K, &As[0][8192], tid, wid, cbs);  // t0 A1
  stage_half(Bg,                    K, &Bs[0][0],    tid, wid, cbs);  // t0 B0
  stage_half(Bg + (size_t)128 * K,  K, &Bs[0][8192], tid, wid, cbs);  // t0 B1
  stage_half(Ag + 64,               K, &As[1][0],    tid, wid, cbs);  // t1 A0
  stage_half(Bg + 64,               K, &Bs[1][0],    tid, wid, cbs);  // t1 B0
  asm volatile("s_waitcnt vmcnt(4)" ::: "memory");   // t0 fully landed
  __builtin_amdgcn_s_barrier();
  __builtin_amdgcn_sched_barrier(0);

  for (int t = 0; t < nt; ++t) {
    unsigned short* Ac = As[t & 1];
    unsigned short* Bc = Bs[t & 1];
    unsigned short* An = As[(t & 1) ^ 1];
    unsigned short* Bn = Bs[(t & 1) ^ 1];
    const int k1 = (t + 1) << 6, k2 = (t + 2) << 6;
    const bool st1 = (t + 1) < nt, st2 = (t + 2) < nt;
    short8 af[4][2], bf[4][2];

    // ===== phase 0: (A0,B0) -> acc[0..3][0..1] =====
#pragma unroll
    for (int mi = 0; mi < 4; ++mi) {
      int rb = (wm * 64 + mi * 16 + l16) * 64;
      af[mi][0] = *(const short8*)&Ac[rb + ca0];
      af[mi][1] = *(const short8*)&Ac[rb + ca1];
    }
#pragma unroll
    for (int ni = 0; ni < 2; ++ni) {
      int rb = (wn * 32 + ni * 16 + l16) * 64;
      bf[ni][0] = *(const short8*)&Bc[rb + ca0];
      bf[ni][1] = *(const short8*)&Bc[rb + ca1];
    }
    if (st1) stage_half(Ag + (size_t)128 * K + k1, K, An + 8192, tid, wid, cbs);
    __builtin_amdgcn_sched_barrier(0);
    __builtin_amdgcn_s_barrier();
    __builtin_amdgcn_sched_barrier(0);
    __builtin_amdgcn_s_setprio(1);
#pragma unroll
    for (int mi = 0; mi < 4; ++mi)
#pragma unroll
      for (int ni = 0; ni < 2; ++ni) {
        acc[mi][ni] = MFMA_BF16(af[mi][0], bf[ni][0], acc[mi][ni]);
        acc[mi][ni] = MFMA_BF16(af[mi][1], bf[ni][1], acc[mi][ni]);
      }
    __builtin_amdgcn_s_setprio(0);
    __builtin_amdgcn_sched_barrier(0);
    __builtin_amdgcn_s_barrier();
    __builtin_amdgcn_sched_barrier(0);

    // ===== phase 1: (A0,B1) -> acc[0..3][2..3] =====
#pragma unroll
    for (int ni = 0; ni < 2; ++ni) {
      int rb = (wn * 32 + ni * 16 + l16) * 64;
      bf[2 + ni][0] = *(const short8*)&Bc[8192 + rb + ca0];
      bf[2 + ni][1] = *(const short8*)&Bc[8192 + rb + ca1];
    }
    if (st1) stage_half(Bg + (size_t)128 * K + k1, K, Bn + 8192, tid, wid, cbs);
    __builtin_amdgcn_sched_barrier(0);
    __builtin_amdgcn_s_barrier();
    __builtin_amdgcn_sched_barrier(0);
    __builtin_amdgcn_s_setprio(1);
#pragma unroll
    for (int mi = 0; mi < 4; ++mi)
#pragma unroll
      for (int ni = 0; ni < 2; ++ni) {
        acc[mi][2 + ni] = MFMA_BF16(af[mi][0], bf[2 + ni][0], acc[mi][2 + ni]);
        acc[mi][2 + ni] = MFMA_BF16(af[mi][1], bf[2 + ni][1], acc[mi][2 + ni]);
      }
    __builtin_amdgcn_s_setprio(0);
    __builtin_amdgcn_sched_barrier(0);
    __builtin_amdgcn_s_barrier();
    __builtin_amdgcn_sched_barrier(0);

    // ===== phase 2: (A1,B0) -> acc[4..7][0..1] =====
#pragma unroll
    for (int mi = 0; mi < 4; ++mi) {
      int rb = (wm * 64 + mi * 16 + l16) * 64;
      af[mi][0] = *(const short8*)&Ac[8192 + rb + ca0];
      af[mi][1] = *(const short8*)&Ac[8192 + rb + ca1];
    }
    if (st2) stage_half(Ag + k2, K, Ac, tid, wid, cbs);   // A0 of t+2
    __builtin_amdgcn_sched_barrier(0);
    __builtin_amdgcn_s_barrier();
    __builtin_amdgcn_sched_barrier(0);
    __builtin_amdgcn_s_setprio(1);
#pragma unroll
    for (int mi = 0; mi < 4; ++mi)
#pragma unroll
      for (int ni = 0; ni < 2; ++ni) {
        acc[4 + mi][ni] = MFMA_BF16(af[mi][0], bf[ni][0], acc[4 + mi][ni]);
        acc[4 + mi][ni] = MFMA_BF16(af[mi][1], bf[ni][1], acc[4 + mi][ni]);
      }
    __builtin_amdgcn_s_setprio(0);
    __builtin_amdgcn_sched_barrier(0);
    __builtin_amdgcn_s_barrier();
    __builtin_amdgcn_sched_barrier(0);

    // ===== phase 3: (A1,B1) -> acc[4..7][2..3] =====
    if (st2) stage_half(Bg + k2, K, Bc, tid, wid, cbs);   // B0 of t+2
    __builtin_amdgcn_sched_barrier(0);
    __builtin_amdgcn_s_barrier();
    __builtin_amdgcn_sched_barrier(0);
    __builtin_amdgcn_s_setprio(1);
#pragma unroll
    for (int mi = 0; mi < 4; ++mi)
#pragma unroll
      for (int ni = 0; ni < 2; ++ni) {
        acc[4 + mi][2 + ni] = MFMA_BF16(af[mi][0], bf[2 + ni][0], acc[4 + mi][2 + ni]);
        acc[4 + mi][2 + ni] = MFMA_BF16(af[mi][1], bf[2 + ni][1], acc[4 + mi][2 + ni]);
      }
    __builtin_amdgcn_s_setprio(0);
    asm volatile("s_waitcnt vmcnt(4)" ::: "memory");
    __builtin_amdgcn_sched_barrier(0);
    __builtin_amdgcn_s_barrier();
    __builtin_amdgcn_sched_barrier(0);
  }

  // ---- epilogue ----
#pragma unroll
  for (int mf = 0; mf < 8; ++mf) {
    int row = brow + (mf >> 2) * 128 + wm * 64 + (mf & 3) * 16 + lg * 4;
#pragma unroll
    for (int nf = 0; nf < 4; ++nf) {
      int col = bcol + (nf >> 1) * 128 + wn * 32 + (nf & 1) * 16 + l16;
      float bv = HAS_BIAS ? bias[col] : 0.f;
      bool vsplit = false;
      if constexpr (SPLIT_V) vsplit = (col >= HID + 512);
      if (vsplit) {
        int vc = col - (HID + 512);
        int vh = vc >> 7, d = vc & 127;
        ushort4 o;
        o.x = f2bf(acc[mf][nf][0] + bv);
        o.y = f2bf(acc[mf][nf][1] + bv);
        o.z = f2bf(acc[mf][nf][2] + bv);
        o.w = f2bf(acc[mf][nf][3] + bv);
        *(ushort4*)&VtOut[(size_t)(vh * DHEAD + d) * S_LEN + row] = o;
      } else {
#pragma unroll
        for (int r = 0; r < 4; ++r) {
          float v = acc[mf][nf][r] + bv;
          if constexpr (OUT_F32)
            ((float*)Cout)[(size_t)(row + r) * N + col] = v;
          else
            ((unsigned short*)Cout)[(size_t)(row + r) * N + col] = f2bf(v);
        }
      }
    }
  }
}

// ---------------- flash attention (causal, GQA 7:1) ----------------
// 64-row q-tiles, LPT dispatch (longest first), 896 blocks.
// K and V^T tiles staged async via global_load_lds (granule XOR-swizzle via
// pre-swizzled source), double-buffered, counted vmcnt(8) prefetch.
__global__ __launch_bounds__(256) void attn(const unsigned short* __restrict__ QKV,
                                            const unsigned short* __restrict__ Vt,
                                            unsigned short* __restrict__ ctx) {
  __shared__ unsigned short Ks[2][64 * 128];   // [buf][kv][d], granule-swizzled
  __shared__ unsigned short Vs[2][128 * 64];   // [buf][d][kv], granule-swizzled
  __shared__ unsigned short Ps[4][16][72];     // per-wave P round-trip
  const int tid = threadIdx.x, wid = tid >> 6, lane = tid & 63;
  const int l16 = lane & 15, lg = lane >> 4;
  const int h = blockIdx.x;
  const int tile = 31 - blockIdx.y;            // LPT: longest blocks dispatched first
  const int kvh = h / GROUPS;
  const float SCALE = 0.08838834764831845f;    // 1/sqrt(128)

  const unsigned short* Kg = QKV + HID + kvh * DHEAD;          // + s*QKV_N
  const unsigned short* Vg = Vt + (size_t)kvh * DHEAD * S_LEN; // + d*S_LEN

  const int qrow = tile * 64 + wid * 16;

  // stage one 64-kv tile: K 1024 granules (16/row), V^T 1024 granules (8/row)
  auto stageKV = [&](int buf, int kt) {
    char* kd = (char*)&Ks[buf][0];
    char* vd = (char*)&Vs[buf][0];
#pragma unroll
    for (int i = 0; i < 4; ++i) {
      int slot = i * 256 + tid;
      {
        int r = slot >> 4, p = slot & 15;
        int lp = p ^ (r & 7);
        gload_lds16(Kg + (size_t)(kt * 64 + r) * QKV_N + lp * 8,
                    kd + i * 4096 + wid * 1024);
      }
      {
        int r = slot >> 3, p = slot & 7;
        int lp = p ^ (r & 7);
        gload_lds16(Vg + (size_t)r * S_LEN + kt * 64 + lp * 8,
                    vd + i * 4096 + wid * 1024);
      }
    }
  };

  short8 qf[4];
#pragma unroll
  for (int kb = 0; kb < 4; ++kb)
    qf[kb] = *(const short8*)&QKV[(size_t)(qrow + l16) * QKV_N + h * DHEAD + kb * 32 + lg * 8];

  f32x4 of[8] = {};
  float mrun[4], lrun[4];
#pragma unroll
  for (int r = 0; r < 4; ++r) { mrun[r] = -INFINITY; lrun[r] = 0.f; }

  const int nkt = tile + 1;
  stageKV(0, 0);
  for (int kt = 0; kt < nkt; ++kt) {
    const int buf = kt & 1;
    if (kt + 1 < nkt) {
      stageKV(buf ^ 1, kt + 1);
      __builtin_amdgcn_sched_barrier(0);
      asm volatile("s_waitcnt vmcnt(8)" ::: "memory");   // current tile landed
    } else {
      __builtin_amdgcn_sched_barrier(0);
      asm volatile("s_waitcnt vmcnt(0)" ::: "memory");
    }
    __builtin_amdgcn_sched_barrier(0);
    __builtin_amdgcn_s_barrier();
    __builtin_amdgcn_sched_barrier(0);

    // ---- S = Q K^T ----
    f32x4 s[4] = {};
    __builtin_amdgcn_s_setprio(1);
#pragma unroll
    for (int kb = 0; kb < 4; ++kb) {
      short8 b[4];
#pragma unroll
      for (int cb = 0; cb < 4; ++cb)
        b[cb] = *(const short8*)&Ks[buf][(cb * 16 + l16) * 128 + ((kb * 4 + lg) ^ (l16 & 7)) * 8];
#pragma unroll
      for (int cb = 0; cb < 4; ++cb)
        s[cb] = MFMA_BF16(qf[kb], b[cb], s[cb]);
    }
    __builtin_amdgcn_s_setprio(0);

    // ---- online softmax (mask only on the diagonal step) ----
    const bool diag = (kt == tile);
    float rmax[4], rsum[4], mnew[4], alpha[4];
#pragma unroll
    for (int r = 0; r < 4; ++r) rmax[r] = -INFINITY;
#pragma unroll
    for (int cb = 0; cb < 4; ++cb)
#pragma unroll
      for (int r = 0; r < 4; ++r) {
        float v = s[cb][r] * SCALE;
        if (diag) {
          int qg = wid * 16 + lg * 4 + r;
          int kg = cb * 16 + l16;
          if (kg > qg) v = -1e30f;
        }
        s[cb][r] = v;
        rmax[r] = fmaxf(rmax[r], v);
      }
#pragma unroll
    for (int r = 0; r < 4; ++r) {
#pragma unroll
      for (int msk = 1; msk < 16; msk <<= 1)
        rmax[r] = fmaxf(rmax[r], __shfl_xor(rmax[r], msk, 64));
      mnew[r] = fmaxf(mrun[r], rmax[r]);
      alpha[r] = __expf(mrun[r] - mnew[r]);
      rsum[r] = 0.f;
    }
#pragma unroll
    for (int cb = 0; cb < 4; ++cb)
#pragma unroll
      for (int r = 0; r < 4; ++r) {
        float p = __expf(s[cb][r] - mnew[r]);
        s[cb][r] = p;
        rsum[r] += p;
      }
#pragma unroll
    for (int r = 0; r < 4; ++r) {
#pragma unroll
      for (int msk = 1; msk < 16; msk <<= 1)
        rsum[r] += __shfl_xor(rsum[r], msk, 64);
      lrun[r] = lrun[r] * alpha[r] + rsum[r];
      mrun[r] = mnew[r];
    }
#pragma unroll
    for (int nb = 0; nb < 8; ++nb)
#pragma unroll
      for (int r = 0; r < 4; ++r) of[nb][r] *= alpha[r];
    {
      const int psw = lg << 4;
#pragma unroll
      for (int cb = 0; cb < 4; ++cb)
#pragma unroll
        for (int r = 0; r < 4; ++r)
          Ps[wid][lg * 4 + r][(cb * 16 + l16) ^ psw] = f2bf(s[cb][r]);
    }

    // ---- PV ----
    __builtin_amdgcn_s_setprio(1);
#pragma unroll
    for (int kb = 0; kb < 2; ++kb) {
      short8 pa = *(const short8*)&Ps[wid][l16][(kb * 32 + lg * 8) ^ ((l16 >> 2) << 4)];
#pragma unroll
      for (int nb = 0; nb < 8; ++nb) {
        short8 vb = *(const short8*)&Vs[buf][(nb * 16 + l16) * 64 + ((kb * 4 + lg) ^ (l16 & 7)) * 8];
        of[nb] = MFMA_BF16(pa, vb, of[nb]);
      }
    }
    __builtin_amdgcn_s_setprio(0);
    __builtin_amdgcn_sched_barrier(0);
    __builtin_amdgcn_s_barrier();
    __builtin_amdgcn_sched_barrier(0);
  }

  // ---- epilogue: ctx[s][h*128+d] ----
#pragma unroll
  for (int r = 0; r < 4; ++r) {
    float inv = 1.f / lrun[r];
    int row = qrow + lg * 4 + r;
#pragma unroll
    for (int nb = 0; nb < 8; ++nb)
      ctx[(size_t)row * HID + h * DHEAD + nb * 16 + l16] = f2bf(of[nb][r] * inv);
  }
}

// ---------------- host launch ----------------
extern "C" void kernel_launch(void* const* d_in, const int* in_sizes, int n_in,
                              void* d_out, int out_size, void* d_ws, size_t ws_size,
                              hipStream_t stream) {
  (void)in_sizes; (void)n_in; (void)out_size; (void)ws_size;
  const float* X   = (const float*)d_in[0];
  const int*   pos = (const int*)d_in[1];
  const float* qw  = (const float*)d_in[2];
  const float* qb  = (const float*)d_in[3];
  const float* kw  = (const float*)d_in[4];
  const float* kb  = (const float*)d_in[5];
  const float* vw  = (const float*)d_in[6];
  const float* vb  = (const float*)d_in[7];
  const float* ow  = (const float*)d_in[8];
  float* out = (float*)d_out;

  char* w = (char*)d_ws;
  unsigned short* Xb    = (unsigned short*)w; w += (size_t)S_LEN * HID * 2;
  unsigned short* Wqkvt = (unsigned short*)w; w += (size_t)QKV_N * HID * 2;
  unsigned short* Wot   = (unsigned short*)w; w += (size_t)HID * HID * 2;
  float*          bqkv  = (float*)w;          w += (size_t)QKV_N * 4;
  unsigned short* QKV   = (unsigned short*)w; w += (size_t)S_LEN * QKV_N * 2;
  unsigned short* VtB   = (unsigned short*)w; w += (size_t)NKV * DHEAD * S_LEN * 2;
  float*          ct    = (float*)w;          w += (size_t)S_LEN * 64 * 4;
  float*          st    = (float*)w;          w += (size_t)S_LEN * 64 * 4;
  unsigned short* ctx   = (unsigned short*)w; w += (size_t)S_LEN * HID * 2;

  conv_f32_bf16<<<2048, 256, 0, stream>>>(X, Xb, S_LEN * HID);
  transpose_conv<<<dim3(112, 112), dim3(32, 8), 0, stream>>>(qw, Wqkvt, HID, HID);
  transpose_conv<<<dim3(16, 112),  dim3(32, 8), 0, stream>>>(kw, Wqkvt + (size_t)HID * HID, HID, 512);
  transpose_conv<<<dim3(16, 112),  dim3(32, 8), 0, stream>>>(vw, Wqkvt + (size_t)(HID + 512) * HID, HID, 512);
  transpose_conv<<<dim3(112, 112), dim3(32, 8), 0, stream>>>(ow, Wot, HID, HID);
  concat_bias<<<18, 256, 0, stream>>>(qb, kb, vb, bqkv);
  rope_table<<<S_LEN, 64, 0, stream>>>(pos, ct, st);

  gemm256<true, false, true><<<dim3(QKV_N / 256, S_LEN / 256), 512, 0, stream>>>(
      Xb, Wqkvt, bqkv, QKV, VtB, S_LEN, QKV_N, HID);
  rope_apply<<<(S_LEN * 32 * 64) / 256, 256, 0, stream>>>(QKV, ct, st);
  attn<<<dim3(NH, 32), 256, 0, stream>>>(QKV, VtB, ctx);
  gemm256<false, true, false><<<dim3(HID / 256, S_LEN / 256), 512, 0, stream>>>(
      ctx, Wot, nullptr, out, nullptr, S_LEN, HID, HID);
}

// Round 6
// 472.319 us; speedup vs baseline: 1.4360x; 1.0003x over previous
//
#include <hip/hip_runtime.h>
#include <cstdint>
#include <cstddef>

// ---------------- problem constants ----------------
#define S_LEN 2048
#define HID   3584
#define NH    28
#define NKV   4
#define DHEAD 128
#define QKV_N 4608   /* 3584 Q + 512 K + 512 V */
#define GROUPS 7

typedef __attribute__((ext_vector_type(8))) short  short8;   // 8 bf16 (4 VGPRs)
typedef __attribute__((ext_vector_type(4))) float  f32x4;    // MFMA accumulator

__device__ __forceinline__ unsigned short f2bf(float f) {
  unsigned int u = __builtin_bit_cast(unsigned int, f);
  u += 0x7FFFu + ((u >> 16) & 1u);            // RNE
  return (unsigned short)(u >> 16);
}
__device__ __forceinline__ float bf2f(unsigned short b) {
  unsigned int u = ((unsigned int)b) << 16;
  return __builtin_bit_cast(float, u);
}
// async global->LDS, 16B/lane. lds ptr must be wave-uniform; HW adds lane*16.
__device__ __forceinline__ void gload_lds16(const void* g, void* l) {
  __builtin_amdgcn_global_load_lds(
      (const __attribute__((address_space(1))) unsigned int*)g,
      (__attribute__((address_space(3))) unsigned int*)l, 16, 0, 0);
}

#define MFMA_BF16(a, b, c) __builtin_amdgcn_mfma_f32_16x16x32_bf16((a), (b), (c), 0, 0, 0)

// ---------------- fp32 -> bf16 elementwise convert ----------------
__global__ void conv_f32_bf16(const float* __restrict__ in,
                              unsigned short* __restrict__ out, int n) {
  int i = (blockIdx.x * blockDim.x + threadIdx.x) * 4;
  int stride = gridDim.x * blockDim.x * 4;
  for (; i < n; i += stride) {
    float4 v = *(const float4*)&in[i];
    ushort4 o;
    o.x = f2bf(v.x); o.y = f2bf(v.y); o.z = f2bf(v.z); o.w = f2bf(v.w);
    *(ushort4*)&out[i] = o;
  }
}

// ------- vectorized transpose + convert: W[K][N] f32 -> Wt[N][K] bf16 -------
// 64x64 tile, 256 threads. float4 coalesced loads; transposed scalar LDS
// stores (2 lanes/bank = free); short8 (16B) coalesced global stores.
__global__ __launch_bounds__(256) void transpose_conv(const float* __restrict__ W,
                                                      unsigned short* __restrict__ Wt,
                                                      int K, int N) {
  __shared__ float t2[64][65];                    // [n][k], pad 65 (conflict-free)
  const int tid = threadIdx.x;
  const int n0 = blockIdx.x * 64, k0 = blockIdx.y * 64;
  const int r = tid >> 4;                         // 0..15 (k row group)
  const int c4 = (tid & 15) * 4;                  // 0..60 (n col group)
#pragma unroll
  for (int i = 0; i < 4; ++i) {
    float4 v = *(const float4*)&W[(size_t)(k0 + r + i * 16) * N + n0 + c4];
    t2[c4 + 0][r + i * 16] = v.x;
    t2[c4 + 1][r + i * 16] = v.y;
    t2[c4 + 2][r + i * 16] = v.z;
    t2[c4 + 3][r + i * 16] = v.w;
  }
  __syncthreads();
  const int k8 = (tid & 7) * 8;
#pragma unroll
  for (int ch = 0; ch < 2; ++ch) {
    int n = (tid >> 3) + ch * 32;
    short8 o;
#pragma unroll
    for (int j = 0; j < 8; ++j) o[j] = (short)f2bf(t2[n][k8 + j]);
    *(short8*)&Wt[(size_t)(n0 + n) * K + k0 + k8] = o;
  }
}

// ---------------- bias concat [q_b | k_b | v_b] -> fp32[4608] ----------------
__global__ void concat_bias(const float* __restrict__ qb, const float* __restrict__ kb,
                            const float* __restrict__ vb, float* __restrict__ out) {
  int i = blockIdx.x * blockDim.x + threadIdx.x;
  if (i < HID) out[i] = qb[i];
  else if (i < HID + 512) out[i] = kb[i - HID];
  else if (i < QKV_N) out[i] = vb[i - HID - 512];
}

// ---------------- RoPE cos/sin table: [2048][64] each ----------------
__global__ void rope_table(const int* __restrict__ pos, float* __restrict__ ct,
                           float* __restrict__ st) {
  int p = blockIdx.x, i = threadIdx.x;            // 64 threads
  float pf = (float)pos[p];
  float inv = __expf(-(float)i * (13.815510557964274f / 64.0f));
  float f = pf * inv;
  ct[p * 64 + i] = cosf(f);
  st[p * 64 + i] = sinf(f);
}

// ---------------- RoPE apply in-place on Q,K halves of QKV ----------------
__global__ void rope_apply(unsigned short* __restrict__ QKV,
                           const float* __restrict__ ct, const float* __restrict__ st) {
  int idx = blockIdx.x * blockDim.x + threadIdx.x;  // 2048 * 32 * 64 total
  int i  = idx & 63;
  int hs = (idx >> 6) & 31;                         // 0..27 Q heads, 28..31 K heads
  int s  = idx >> 11;
  int cb = hs < NH ? hs * DHEAD : HID + (hs - NH) * DHEAD;
  size_t base = (size_t)s * QKV_N + cb;
  float x1 = bf2f(QKV[base + i]);
  float x2 = bf2f(QKV[base + 64 + i]);
  float c = ct[s * 64 + i], sn = st[s * 64 + i];
  QKV[base + i]      = f2bf(x1 * c - x2 * sn);
  QKV[base + 64 + i] = f2bf(x2 * c + x1 * sn);
}

// ================= 256x256 8-phase bf16 GEMM (m201 template port) =============
// C[M][N] = A[M][K] @ Bt[N][K]^T (+bias). 512 threads = 8 waves (2M x 4N).
// T1 XCD swizzle (grids are multiples of 8). SPLIT_V: cols >= 4096 written
// transposed to VtOut[vh][d][s] for attention.
__device__ __forceinline__ void stage_half(const unsigned short* g, int K,
                                           unsigned short* lds, int tid, int wid,
                                           int cbs) {
#pragma unroll
  for (int i = 0; i < 2; ++i) {
    int row = (i * 512 + tid) >> 3;
    gload_lds16(g + (size_t)row * K + cbs * 8,
                (char*)lds + (size_t)(i * 512 + wid * 64) * 16);
  }
}

template <bool HAS_BIAS, bool OUT_F32, bool SPLIT_V>
__global__ __launch_bounds__(512, 2) void gemm256(
    const unsigned short* __restrict__ A, const unsigned short* __restrict__ Bt,
    const float* __restrict__ bias, void* __restrict__ Cout,
    unsigned short* __restrict__ VtOut, int M, int N, int K) {
  __shared__ unsigned short As[2][16384];   // [buf][256 rows x 64 k], swizzled granules
  __shared__ unsigned short Bs[2][16384];
  const int tid = threadIdx.x, wid = tid >> 6, lane = tid & 63;
  const int l16 = lane & 15, lg = lane >> 4;
  const int wm = wid >> 2, wn = wid & 3;
  // T1: XCD-aware bijective swizzle (nwg % 8 == 0 for all our grids)
  const int nwg = gridDim.x * gridDim.y;
  const int bidx = blockIdx.y * gridDim.x + blockIdx.x;
  const int swz = (bidx & 7) * (nwg >> 3) + (bidx >> 3);
  const int bx = swz % gridDim.x, by = swz / gridDim.x;
  const int brow = by * 256, bcol = bx * 256;
  const int cbs = (tid & 7) ^ ((tid >> 3) & 7);
  const int ca0 = ((0 + lg) ^ (l16 & 7)) * 8;   // ks=0 granule col (elements)
  const int ca1 = ((4 + lg) ^ (l16 & 7)) * 8;   // ks=1

  const unsigned short* Ag = A + (size_t)brow * K;
  const unsigned short* Bg = Bt + (size_t)bcol * K;

  f32x4 acc[8][4] = {};
  const int nt = K >> 6;

  stage_half(Ag,                    K, &As[0][0],    tid, wid, cbs);  // t0 A0
  stage_half(Ag + (size_t)128 * K,  K, &As[0][8192], tid, wid, cbs);  // t0 A1
  stage_half(Bg,                    K, &Bs[0][0],    tid, wid, cbs);  // t0 B0
  stage_half(Bg + (size_t)128 * K,  K, &Bs[0][8192], tid, wid, cbs);  // t0 B1
  stage_half(Ag + 64,               K, &As[1][0],    tid, wid, cbs);  // t1 A0
  stage_half(Bg + 64,               K, &Bs[1][0],    tid, wid, cbs);  // t1 B0
  asm volatile("s_waitcnt vmcnt(4)" ::: "memory");   // t0 fully landed
  __builtin_amdgcn_s_barrier();
  __builtin_amdgcn_sched_barrier(0);

  for (int t = 0; t < nt; ++t) {
    unsigned short* Ac = As[t & 1];
    unsigned short* Bc = Bs[t & 1];
    unsigned short* An = As[(t & 1) ^ 1];
    unsigned short* Bn = Bs[(t & 1) ^ 1];
    const int k1 = (t + 1) << 6, k2 = (t + 2) << 6;
    const bool st1 = (t + 1) < nt, st2 = (t + 2) < nt;
    short8 af[4][2], bf[4][2];

    // ===== phase 0: (A0,B0) -> acc[0..3][0..1] =====
#pragma unroll
    for (int mi = 0; mi < 4; ++mi) {
      int rb = (wm * 64 + mi * 16 + l16) * 64;
      af[mi][0] = *(const short8*)&Ac[rb + ca0];
      af[mi][1] = *(const short8*)&Ac[rb + ca1];
    }
#pragma unroll
    for (int ni = 0; ni < 2; ++ni) {
      int rb = (wn * 32 + ni * 16 + l16) * 64;
      bf[ni][0] = *(const short8*)&Bc[rb + ca0];
      bf[ni][1] = *(const short8*)&Bc[rb + ca1];
    }
    if (st1) stage_half(Ag + (size_t)128 * K + k1, K, An + 8192, tid, wid, cbs);
    __builtin_amdgcn_sched_barrier(0);
    __builtin_amdgcn_s_barrier();
    __builtin_amdgcn_sched_barrier(0);
    __builtin_amdgcn_s_setprio(1);
#pragma unroll
    for (int mi = 0; mi < 4; ++mi)
#pragma unroll
      for (int ni = 0; ni < 2; ++ni) {
        acc[mi][ni] = MFMA_BF16(af[mi][0], bf[ni][0], acc[mi][ni]);
        acc[mi][ni] = MFMA_BF16(af[mi][1], bf[ni][1], acc[mi][ni]);
      }
    __builtin_amdgcn_s_setprio(0);
    __builtin_amdgcn_sched_barrier(0);
    __builtin_amdgcn_s_barrier();
    __builtin_amdgcn_sched_barrier(0);

    // ===== phase 1: (A0,B1) -> acc[0..3][2..3] =====
#pragma unroll
    for (int ni = 0; ni < 2; ++ni) {
      int rb = (wn * 32 + ni * 16 + l16) * 64;
      bf[2 + ni][0] = *(const short8*)&Bc[8192 + rb + ca0];
      bf[2 + ni][1] = *(const short8*)&Bc[8192 + rb + ca1];
    }
    if (st1) stage_half(Bg + (size_t)128 * K + k1, K, Bn + 8192, tid, wid, cbs);
    __builtin_amdgcn_sched_barrier(0);
    __builtin_amdgcn_s_barrier();
    __builtin_amdgcn_sched_barrier(0);
    __builtin_amdgcn_s_setprio(1);
#pragma unroll
    for (int mi = 0; mi < 4; ++mi)
#pragma unroll
      for (int ni = 0; ni < 2; ++ni) {
        acc[mi][2 + ni] = MFMA_BF16(af[mi][0], bf[2 + ni][0], acc[mi][2 + ni]);
        acc[mi][2 + ni] = MFMA_BF16(af[mi][1], bf[2 + ni][1], acc[mi][2 + ni]);
      }
    __builtin_amdgcn_s_setprio(0);
    __builtin_amdgcn_sched_barrier(0);
    __builtin_amdgcn_s_barrier();
    __builtin_amdgcn_sched_barrier(0);

    // ===== phase 2: (A1,B0) -> acc[4..7][0..1] =====
#pragma unroll
    for (int mi = 0; mi < 4; ++mi) {
      int rb = (wm * 64 + mi * 16 + l16) * 64;
      af[mi][0] = *(const short8*)&Ac[8192 + rb + ca0];
      af[mi][1] = *(const short8*)&Ac[8192 + rb + ca1];
    }
    if (st2) stage_half(Ag + k2, K, Ac, tid, wid, cbs);   // A0 of t+2
    __builtin_amdgcn_sched_barrier(0);
    __builtin_amdgcn_s_barrier();
    __builtin_amdgcn_sched_barrier(0);
    __builtin_amdgcn_s_setprio(1);
#pragma unroll
    for (int mi = 0; mi < 4; ++mi)
#pragma unroll
      for (int ni = 0; ni < 2; ++ni) {
        acc[4 + mi][ni] = MFMA_BF16(af[mi][0], bf[ni][0], acc[4 + mi][ni]);
        acc[4 + mi][ni] = MFMA_BF16(af[mi][1], bf[ni][1], acc[4 + mi][ni]);
      }
    __builtin_amdgcn_s_setprio(0);
    __builtin_amdgcn_sched_barrier(0);
    __builtin_amdgcn_s_barrier();
    __builtin_amdgcn_sched_barrier(0);

    // ===== phase 3: (A1,B1) -> acc[4..7][2..3] =====
    if (st2) stage_half(Bg + k2, K, Bc, tid, wid, cbs);   // B0 of t+2
    __builtin_amdgcn_sched_barrier(0);
    __builtin_amdgcn_s_barrier();
    __builtin_amdgcn_sched_barrier(0);
    __builtin_amdgcn_s_setprio(1);
#pragma unroll
    for (int mi = 0; mi < 4; ++mi)
#pragma unroll
      for (int ni = 0; ni < 2; ++ni) {
        acc[4 + mi][2 + ni] = MFMA_BF16(af[mi][0], bf[2 + ni][0], acc[4 + mi][2 + ni]);
        acc[4 + mi][2 + ni] = MFMA_BF16(af[mi][1], bf[2 + ni][1], acc[4 + mi][2 + ni]);
      }
    __builtin_amdgcn_s_setprio(0);
    asm volatile("s_waitcnt vmcnt(4)" ::: "memory");
    __builtin_amdgcn_sched_barrier(0);
    __builtin_amdgcn_s_barrier();
    __builtin_amdgcn_sched_barrier(0);
  }

  // ---- epilogue ----
#pragma unroll
  for (int mf = 0; mf < 8; ++mf) {
    int row = brow + (mf >> 2) * 128 + wm * 64 + (mf & 3) * 16 + lg * 4;
#pragma unroll
    for (int nf = 0; nf < 4; ++nf) {
      int col = bcol + (nf >> 1) * 128 + wn * 32 + (nf & 1) * 16 + l16;
      float bv = HAS_BIAS ? bias[col] : 0.f;
      bool vsplit = false;
      if constexpr (SPLIT_V) vsplit = (col >= HID + 512);
      if (vsplit) {
        int vc = col - (HID + 512);
        int vh = vc >> 7, d = vc & 127;
        ushort4 o;
        o.x = f2bf(acc[mf][nf][0] + bv);
        o.y = f2bf(acc[mf][nf][1] + bv);
        o.z = f2bf(acc[mf][nf][2] + bv);
        o.w = f2bf(acc[mf][nf][3] + bv);
        *(ushort4*)&VtOut[(size_t)(vh * DHEAD + d) * S_LEN + row] = o;
      } else {
#pragma unroll
        for (int r = 0; r < 4; ++r) {
          float v = acc[mf][nf][r] + bv;
          if constexpr (OUT_F32)
            ((float*)Cout)[(size_t)(row + r) * N + col] = v;
          else
            ((unsigned short*)Cout)[(size_t)(row + r) * N + col] = f2bf(v);
        }
      }
    }
  }
}

// ---------------- flash attention (causal, GQA 7:1) ----------------
// 64-row q-tiles, LPT dispatch (longest first), 896 blocks.
// K and V^T tiles staged async via global_load_lds (granule XOR-swizzle via
// pre-swizzled source), double-buffered, counted vmcnt(8) prefetch.
__global__ __launch_bounds__(256) void attn(const unsigned short* __restrict__ QKV,
                                            const unsigned short* __restrict__ Vt,
                                            unsigned short* __restrict__ ctx) {
  __shared__ unsigned short Ks[2][64 * 128];   // [buf][kv][d], granule-swizzled
  __shared__ unsigned short Vs[2][128 * 64];   // [buf][d][kv], granule-swizzled
  __shared__ unsigned short Ps[4][16][72];     // per-wave P round-trip
  const int tid = threadIdx.x, wid = tid >> 6, lane = tid & 63;
  const int l16 = lane & 15, lg = lane >> 4;
  const int h = blockIdx.x;
  const int tile = 31 - blockIdx.y;            // LPT: longest blocks dispatched first
  const int kvh = h / GROUPS;
  const float SCALE = 0.08838834764831845f;    // 1/sqrt(128)

  const unsigned short* Kg = QKV + HID + kvh * DHEAD;          // + s*QKV_N
  const unsigned short* Vg = Vt + (size_t)kvh * DHEAD * S_LEN; // + d*S_LEN

  const int qrow = tile * 64 + wid * 16;

  auto stageKV = [&](int buf, int kt) {
    char* kd = (char*)&Ks[buf][0];
    char* vd = (char*)&Vs[buf][0];
#pragma unroll
    for (int i = 0; i < 4; ++i) {
      int slot = i * 256 + tid;
      {
        int r = slot >> 4, p = slot & 15;
        int lp = p ^ (r & 7);
        gload_lds16(Kg + (size_t)(kt * 64 + r) * QKV_N + lp * 8,
                    kd + i * 4096 + wid * 1024);
      }
      {
        int r = slot >> 3, p = slot & 7;
        int lp = p ^ (r & 7);
        gload_lds16(Vg + (size_t)r * S_LEN + kt * 64 + lp * 8,
                    vd + i * 4096 + wid * 1024);
      }
    }
  };

  short8 qf[4];
#pragma unroll
  for (int kb = 0; kb < 4; ++kb)
    qf[kb] = *(const short8*)&QKV[(size_t)(qrow + l16) * QKV_N + h * DHEAD + kb * 32 + lg * 8];

  f32x4 of[8] = {};
  float mrun[4], lrun[4];
#pragma unroll
  for (int r = 0; r < 4; ++r) { mrun[r] = -INFINITY; lrun[r] = 0.f; }

  const int nkt = tile + 1;
  stageKV(0, 0);
  for (int kt = 0; kt < nkt; ++kt) {
    const int buf = kt & 1;
    if (kt + 1 < nkt) {
      stageKV(buf ^ 1, kt + 1);
      __builtin_amdgcn_sched_barrier(0);
      asm volatile("s_waitcnt vmcnt(8)" ::: "memory");   // current tile landed
    } else {
      __builtin_amdgcn_sched_barrier(0);
      asm volatile("s_waitcnt vmcnt(0)" ::: "memory");
    }
    __builtin_amdgcn_sched_barrier(0);
    __builtin_amdgcn_s_barrier();
    __builtin_amdgcn_sched_barrier(0);

    // ---- S = Q K^T ----
    f32x4 s[4] = {};
    __builtin_amdgcn_s_setprio(1);
#pragma unroll
    for (int kb = 0; kb < 4; ++kb) {
      short8 b[4];
#pragma unroll
      for (int cb = 0; cb < 4; ++cb)
        b[cb] = *(const short8*)&Ks[buf][(cb * 16 + l16) * 128 + ((kb * 4 + lg) ^ (l16 & 7)) * 8];
#pragma unroll
      for (int cb = 0; cb < 4; ++cb)
        s[cb] = MFMA_BF16(qf[kb], b[cb], s[cb]);
    }
    __builtin_amdgcn_s_setprio(0);

    // ---- online softmax (mask only on the diagonal step) ----
    const bool diag = (kt == tile);
    float rmax[4], rsum[4], mnew[4], alpha[4];
#pragma unroll
    for (int r = 0; r < 4; ++r) rmax[r] = -INFINITY;
#pragma unroll
    for (int cb = 0; cb < 4; ++cb)
#pragma unroll
      for (int r = 0; r < 4; ++r) {
        float v = s[cb][r] * SCALE;
        if (diag) {
          int qg = wid * 16 + lg * 4 + r;
          int kg = cb * 16 + l16;
          if (kg > qg) v = -1e30f;
        }
        s[cb][r] = v;
        rmax[r] = fmaxf(rmax[r], v);
      }
#pragma unroll
    for (int r = 0; r < 4; ++r) {
#pragma unroll
      for (int msk = 1; msk < 16; msk <<= 1)
        rmax[r] = fmaxf(rmax[r], __shfl_xor(rmax[r], msk, 64));
      mnew[r] = fmaxf(mrun[r], rmax[r]);
      alpha[r] = __expf(mrun[r] - mnew[r]);
      rsum[r] = 0.f;
    }
#pragma unroll
    for (int cb = 0; cb < 4; ++cb)
#pragma unroll
      for (int r = 0; r < 4; ++r) {
        float p = __expf(s[cb][r] - mnew[r]);
        s[cb][r] = p;
        rsum[r] += p;
      }
#pragma unroll
    for (int r = 0; r < 4; ++r) {
#pragma unroll
      for (int msk = 1; msk < 16; msk <<= 1)
        rsum[r] += __shfl_xor(rsum[r], msk, 64);
      lrun[r] = lrun[r] * alpha[r] + rsum[r];
      mrun[r] = mnew[r];
    }
#pragma unroll
    for (int nb = 0; nb < 8; ++nb)
#pragma unroll
      for (int r = 0; r < 4; ++r) of[nb][r] *= alpha[r];
    {
      const int psw = lg << 4;
#pragma unroll
      for (int cb = 0; cb < 4; ++cb)
#pragma unroll
        for (int r = 0; r < 4; ++r)
          Ps[wid][lg * 4 + r][(cb * 16 + l16) ^ psw] = f2bf(s[cb][r]);
    }

    // ---- PV ----
    __builtin_amdgcn_s_setprio(1);
#pragma unroll
    for (int kb = 0; kb < 2; ++kb) {
      short8 pa = *(const short8*)&Ps[wid][l16][(kb * 32 + lg * 8) ^ ((l16 >> 2) << 4)];
#pragma unroll
      for (int nb = 0; nb < 8; ++nb) {
        short8 vb = *(const short8*)&Vs[buf][(nb * 16 + l16) * 64 + ((kb * 4 + lg) ^ (l16 & 7)) * 8];
        of[nb] = MFMA_BF16(pa, vb, of[nb]);
      }
    }
    __builtin_amdgcn_s_setprio(0);
    __builtin_amdgcn_sched_barrier(0);
    __builtin_amdgcn_s_barrier();
    __builtin_amdgcn_sched_barrier(0);
  }

  // ---- epilogue: ctx[s][h*128+d] ----
#pragma unroll
  for (int r = 0; r < 4; ++r) {
    float inv = 1.f / lrun[r];
    int row = qrow + lg * 4 + r;
#pragma unroll
    for (int nb = 0; nb < 8; ++nb)
      ctx[(size_t)row * HID + h * DHEAD + nb * 16 + l16] = f2bf(of[nb][r] * inv);
  }
}

// ---------------- host launch ----------------
extern "C" void kernel_launch(void* const* d_in, const int* in_sizes, int n_in,
                              void* d_out, int out_size, void* d_ws, size_t ws_size,
                              hipStream_t stream) {
  (void)in_sizes; (void)n_in; (void)out_size; (void)ws_size;
  const float* X   = (const float*)d_in[0];
  const int*   pos = (const int*)d_in[1];
  const float* qw  = (const float*)d_in[2];
  const float* qb  = (const float*)d_in[3];
  const float* kw  = (const float*)d_in[4];
  const float* kb  = (const float*)d_in[5];
  const float* vw  = (const float*)d_in[6];
  const float* vb  = (const float*)d_in[7];
  const float* ow  = (const float*)d_in[8];
  float* out = (float*)d_out;

  char* w = (char*)d_ws;
  unsigned short* Xb    = (unsigned short*)w; w += (size_t)S_LEN * HID * 2;
  unsigned short* Wqkvt = (unsigned short*)w; w += (size_t)QKV_N * HID * 2;
  unsigned short* Wot   = (unsigned short*)w; w += (size_t)HID * HID * 2;
  float*          bqkv  = (float*)w;          w += (size_t)QKV_N * 4;
  unsigned short* QKV   = (unsigned short*)w; w += (size_t)S_LEN * QKV_N * 2;
  unsigned short* VtB   = (unsigned short*)w; w += (size_t)NKV * DHEAD * S_LEN * 2;
  float*          ct    = (float*)w;          w += (size_t)S_LEN * 64 * 4;
  float*          st    = (float*)w;          w += (size_t)S_LEN * 64 * 4;
  unsigned short* ctx   = (unsigned short*)w; w += (size_t)S_LEN * HID * 2;

  conv_f32_bf16<<<2048, 256, 0, stream>>>(X, Xb, S_LEN * HID);
  transpose_conv<<<dim3(56, 56), 256, 0, stream>>>(qw, Wqkvt, HID, HID);
  transpose_conv<<<dim3(8, 56),  256, 0, stream>>>(kw, Wqkvt + (size_t)HID * HID, HID, 512);
  transpose_conv<<<dim3(8, 56),  256, 0, stream>>>(vw, Wqkvt + (size_t)(HID + 512) * HID, HID, 512);
  transpose_conv<<<dim3(56, 56), 256, 0, stream>>>(ow, Wot, HID, HID);
  concat_bias<<<18, 256, 0, stream>>>(qb, kb, vb, bqkv);
  rope_table<<<S_LEN, 64, 0, stream>>>(pos, ct, st);

  gemm256<true, false, true><<<dim3(QKV_N / 256, S_LEN / 256), 512, 0, stream>>>(
      Xb, Wqkvt, bqkv, QKV, VtB, S_LEN, QKV_N, HID);
  rope_apply<<<(S_LEN * 32 * 64) / 256, 256, 0, stream>>>(QKV, ct, st);
  attn<<<dim3(NH, 32), 256, 0, stream>>>(QKV, VtB, ctx);
  gemm256<false, true, false><<<dim3(HID / 256, S_LEN / 256), 512, 0, stream>>>(
      ctx, Wot, nullptr, out, nullptr, S_LEN, HID, HID);
}